// Round 1
// baseline (1908.781 us; speedup 1.0000x reference)
//
#include <hip/hip_runtime.h>
#include <cmath>

#define NA 76725
#define NCLS 80
#define NB 4
#define KC 512
#define MPC 100
#define MT 100

struct Dims { float d[5 * 9 * 2]; };

// ---- helpers -------------------------------------------------------------

__device__ __forceinline__ unsigned keyof(float x) {
    unsigned u = __float_as_uint(x);
    return u ^ ((u & 0x80000000u) ? 0xFFFFFFFFu : 0x80000000u);
}
__device__ __forceinline__ float unkey(unsigned k) {
    unsigned u = (k & 0x80000000u) ? (k ^ 0x80000000u) : ~k;
    return __uint_as_float(u);
}
__device__ __forceinline__ float sigmoidf_dev(float x) {
    if (x >= 0.f) return 1.f / (1.f + expf(-x));
    float e = expf(x);
    return e / (1.f + e);
}

// ---- kernel 1: box decode ------------------------------------------------

__global__ __launch_bounds__(256) void decode_kernel(const float* __restrict__ pred,
                                                     float4* __restrict__ boxes, Dims dims) {
    int g = blockIdx.x * 256 + threadIdx.x;
    if (g >= NB * NA) return;
    int b = g / NA, a = g - b * NA;
    const int base[5] = {0, 57600, 72000, 75600, 76500};
    const int fw[5] = {80, 40, 20, 10, 5};
    const float strd[5] = {8.f, 16.f, 32.f, 64.f, 128.f};
    int l;
    if (a < 57600) l = 0;
    else if (a < 72000) l = 1;
    else if (a < 75600) l = 2;
    else if (a < 76500) l = 3;
    else l = 4;
    int i = a - base[l];
    int cell = i / 9, k = i - cell * 9;
    int x = cell % fw[l], y = cell / fw[l];
    float cx = ((float)x + 0.5f) * strd[l];
    float cy = ((float)y + 0.5f) * strd[l];
    float aw = dims.d[(l * 9 + k) * 2 + 0];
    float ah = dims.d[(l * 9 + k) * 2 + 1];
    const float4 p = *reinterpret_cast<const float4*>(pred + (size_t)g * 84 + 80);
    float bx = __fmul_rn(p.x, 0.1f), by = __fmul_rn(p.y, 0.1f);
    float bw = __fmul_rn(p.z, 0.2f), bh = __fmul_rn(p.w, 0.2f);
    float4 o;
    o.x = __fadd_rn(__fmul_rn(bx, aw), cx);
    o.y = __fadd_rn(__fmul_rn(by, ah), cy);
    o.z = __fmul_rn(expf(bw), aw);
    o.w = __fmul_rn(expf(bh), ah);
    boxes[g] = o;
}

// ---- kernel 2: per-column radix-select top-512 + sort --------------------

__global__ __launch_bounds__(1024) void topk_kernel(const float* __restrict__ pred,
                                                    int* __restrict__ top_idx,
                                                    float* __restrict__ top_score) {
    const int col = blockIdx.x;           // b*80 + c
    const int b = col / NCLS, c = col - b * NCLS;
    const float* colp = pred + (size_t)b * NA * 84 + c;
    const int tid = threadIdx.x;

    __shared__ int hist[256];
    __shared__ unsigned long long buf[KC];
    __shared__ int sh_bsel, sh_above, sh_ceq;
    __shared__ int gcount, eqtaken;
    __shared__ int wcnt[16];

    unsigned prefix = 0;
    int remaining = KC, ceq = 0;

    for (int pass = 0; pass < 4; ++pass) {
        int shift = 24 - 8 * pass;
        unsigned mask_done = (pass == 0) ? 0u : (0xFFFFFFFFu << (shift + 8));
        if (tid < 256) hist[tid] = 0;
        __syncthreads();
        for (int a = tid; a < NA; a += 1024) {
            unsigned key = keyof(colp[(size_t)a * 84]);
            if ((key & mask_done) == prefix)
                atomicAdd(&hist[(key >> shift) & 0xFF], 1);
        }
        __syncthreads();
        if (tid == 0) {
            int cum = 0, bsel = 0, above = 0, cnt = 0;
            for (int bin = 255; bin >= 0; --bin) {
                int cc = hist[bin];
                if (cum + cc >= remaining) { bsel = bin; above = cum; cnt = cc; break; }
                cum += cc;
            }
            sh_bsel = bsel; sh_above = above; sh_ceq = cnt;
        }
        __syncthreads();
        prefix |= ((unsigned)sh_bsel) << shift;
        remaining -= sh_above;
        ceq = sh_ceq;
    }

    const unsigned K = prefix;
    const int cgt = KC - remaining;
    const int need = remaining;
    if (tid == 0) { gcount = 0; eqtaken = 0; }
    __syncthreads();

    if (ceq == need) {
        // fast path: every ==K element is taken, order fixed by the final sort
        for (int a = tid; a < NA; a += 1024) {
            unsigned key = keyof(colp[(size_t)a * 84]);
            if (key > K) {
                int p = atomicAdd(&gcount, 1);
                buf[p] = ((unsigned long long)key << 32) | (unsigned long long)(0xFFFFFFFFu - (unsigned)a);
            } else if (key == K) {
                int p = atomicAdd(&eqtaken, 1);
                buf[cgt + p] = ((unsigned long long)K << 32) | (unsigned long long)(0xFFFFFFFFu - (unsigned)a);
            }
        }
        __syncthreads();
    } else {
        // slow path: pick the smallest-index `need` elements among ==K (ordered scan)
        for (int bs = 0; bs < NA; bs += 1024) {
            int a = bs + tid;
            bool in = a < NA;
            unsigned key = in ? keyof(colp[(size_t)a * 84]) : 0u;
            if (in && key > K) {
                int p = atomicAdd(&gcount, 1);
                buf[p] = ((unsigned long long)key << 32) | (unsigned long long)(0xFFFFFFFFu - (unsigned)a);
            }
            bool eq = in && (key == K);
            unsigned long long m = __ballot(eq);
            int wave = tid >> 6, lane = tid & 63;
            if (lane == 0) wcnt[wave] = __popcll(m);
            __syncthreads();
            int off = eqtaken;
            for (int w = 0; w < wave; ++w) off += wcnt[w];
            int rank = off + __popcll(m & ((1ull << lane) - 1ull));
            if (eq && rank < need)
                buf[cgt + rank] = ((unsigned long long)K << 32) | (unsigned long long)(0xFFFFFFFFu - (unsigned)a);
            __syncthreads();
            if (tid == 0) {
                int s = 0;
                for (int w = 0; w < 16; ++w) s += wcnt[w];
                eqtaken += s;
            }
            __syncthreads();
        }
    }

    // bitonic sort 512, descending by (key desc, idx asc) via composite
    for (int k2 = 2; k2 <= KC; k2 <<= 1) {
        for (int j = k2 >> 1; j > 0; j >>= 1) {
            __syncthreads();
            if (tid < KC) {
                int i = tid, ixj = i ^ j;
                if (ixj > i) {
                    unsigned long long A = buf[i], B = buf[ixj];
                    bool up = (i & k2) == 0;
                    if (up ? (A < B) : (A > B)) { buf[i] = B; buf[ixj] = A; }
                }
            }
        }
    }
    __syncthreads();
    if (tid < KC) {
        unsigned long long v = buf[tid];
        unsigned key = (unsigned)(v >> 32);
        int a = (int)(0xFFFFFFFFu - (unsigned)(v & 0xFFFFFFFFu));
        top_idx[col * KC + tid] = a;
        top_score[col * KC + tid] = sigmoidf_dev(unkey(key));
    }
}

// ---- kernel 3: greedy NMS + first-100 compaction -------------------------

__global__ __launch_bounds__(256) void nms_kernel(const float4* __restrict__ boxes,
                                                  const int* __restrict__ top_idx,
                                                  const float* __restrict__ top_score,
                                                  float4* __restrict__ col_boxes,
                                                  float* __restrict__ col_scores) {
    const int col = blockIdx.x, b = col / NCLS;
    const int tid = threadIdx.x;
    __shared__ float y1[KC], x1[KC], y2[KC], x2[KC], ar[KC], sc[KC];
    __shared__ int keep[KC];
    __shared__ int sel[MPC];

    for (int t = tid; t < KC; t += 256) {
        int idx = top_idx[col * KC + t];
        float4 bx = boxes[(size_t)b * NA + idx];
        y1[t] = bx.x; x1[t] = bx.y; y2[t] = bx.z; x2[t] = bx.w;
        ar[t] = __fmul_rn(fmaxf(__fsub_rn(bx.z, bx.x), 0.f),
                          fmaxf(__fsub_rn(bx.w, bx.y), 0.f));
        float s = top_score[col * KC + t];
        sc[t] = s;
        keep[t] = (s > 0.05f) ? 1 : 0;
    }
    __syncthreads();

    for (int i = 0; i < KC; ++i) {
        if (keep[i]) {  // uniform branch: all threads read same LDS value
            float Y1 = y1[i], X1 = x1[i], Y2 = y2[i], X2 = x2[i], AR = ar[i];
            for (int j = i + 1 + tid; j < KC; j += 256) {
                float ih = fmaxf(__fsub_rn(fminf(Y2, y2[j]), fmaxf(Y1, y1[j])), 0.f);
                float iw = fmaxf(__fsub_rn(fminf(X2, x2[j]), fmaxf(X1, x1[j])), 0.f);
                float inter = __fmul_rn(ih, iw);
                float uni = __fsub_rn(__fadd_rn(AR, ar[j]), inter);
                float iou = (uni > 0.f) ? __fdiv_rn(inter, uni) : 0.f;
                if (iou > 0.5f) keep[j] = 0;
            }
        }
        __syncthreads();
    }

    if (tid == 0) {
        int n = 0;
        for (int t = 0; t < KC && n < MPC; ++t) if (keep[t]) sel[n++] = t;
        for (int t = 0; t < KC && n < MPC; ++t) if (!keep[t]) sel[n++] = t;
    }
    __syncthreads();
    if (tid < MPC) {
        int t = sel[tid];
        col_scores[col * MPC + tid] = keep[t] ? sc[t] : 0.f;
        float4 o; o.x = y1[t]; o.y = x1[t]; o.z = y2[t]; o.w = x2[t];
        col_boxes[col * MPC + tid] = o;
    }
}

// ---- kernel 4: per-batch combine (bitonic sort of 8192) ------------------

__global__ __launch_bounds__(256) void combine_kernel(const float4* __restrict__ col_boxes,
                                                      const float* __restrict__ col_scores,
                                                      float* __restrict__ out) {
    const int b = blockIdx.x, tid = threadIdx.x;
    __shared__ unsigned long long buf[8192];  // exactly 64 KiB

    for (int t = tid; t < 8192; t += 256) {
        unsigned long long v = 0ull;
        if (t < NCLS * MPC) {
            float s = col_scores[b * NCLS * MPC + t];
            v = ((unsigned long long)__float_as_uint(s) << 32) |
                (unsigned long long)(0xFFFFFFFFu - (unsigned)t);
        }
        buf[t] = v;
    }
    for (int k2 = 2; k2 <= 8192; k2 <<= 1) {
        for (int j = k2 >> 1; j > 0; j >>= 1) {
            __syncthreads();
            for (int i = tid; i < 8192; i += 256) {
                int ixj = i ^ j;
                if (ixj > i) {
                    unsigned long long A = buf[i], B = buf[ixj];
                    bool up = (i & k2) == 0;
                    if (up ? (A < B) : (A > B)) { buf[i] = B; buf[ixj] = A; }
                }
            }
        }
    }
    __syncthreads();
    unsigned long long v = (tid < MT) ? buf[tid] : 0ull;
    __syncthreads();
    int* scnt = (int*)buf;  // reuse LDS slot as counter (buf no longer needed)
    if (tid == 0) *scnt = 0;
    __syncthreads();
    if (tid < MT) {
        float s = __uint_as_float((unsigned)(v >> 32));
        int f = (int)(0xFFFFFFFFu - (unsigned)(v & 0xFFFFFFFFu));
        bool valid = (s > 0.f);
        int cl = 0, p = 0;
        float4 bx = make_float4(0.f, 0.f, 0.f, 0.f);
        if (valid) {
            cl = f / MPC;
            p = f - cl * MPC;
            float4 raw = col_boxes[((size_t)b * NCLS + cl) * MPC + p];
            bx.x = fminf(fmaxf(raw.x, 0.f), 1.f);
            bx.y = fminf(fmaxf(raw.y, 0.f), 1.f);
            bx.z = fminf(fmaxf(raw.z, 0.f), 1.f);
            bx.w = fminf(fmaxf(raw.w, 0.f), 1.f);
            atomicAdd(scnt, 1);
        }
        int o = b * MT + tid;
        out[o * 4 + 0] = bx.x;
        out[o * 4 + 1] = bx.y;
        out[o * 4 + 2] = bx.z;
        out[o * 4 + 3] = bx.w;
        out[NB * MT * 4 + o] = valid ? s : 0.f;
        out[NB * MT * 5 + o] = valid ? (float)cl : 0.f;
    }
    __syncthreads();
    if (tid == 0) out[NB * MT * 6 + b] = (float)(*scnt);
}

// ---- launch --------------------------------------------------------------

extern "C" void kernel_launch(void* const* d_in, const int* in_sizes, int n_in,
                              void* d_out, int out_size, void* d_ws, size_t ws_size,
                              hipStream_t stream) {
    const float* pred = (const float*)d_in[1];
    float* out = (float*)d_out;
    char* ws = (char*)d_ws;

    float4* boxes      = (float4*)(ws);                 // 306900*16 = 4,910,400 B
    int*    top_idx    = (int*)  (ws + 4910400);        // 320*512*4 =   655,360 B
    float*  top_score  = (float*)(ws + 5565760);        // 320*512*4 =   655,360 B
    float4* col_boxes  = (float4*)(ws + 6221120);       // 320*100*16 =  512,000 B
    float*  col_scores = (float*)(ws + 6733120);        // 320*100*4 =   128,000 B

    // anchor dims in float64 exactly like the numpy reference, cast to fp32
    Dims dims;
    const double ratios[3] = {0.5, 1.0, 2.0};
    for (int l = 0; l < 5; ++l) {
        double side = (double)(1 << (l + 5));   // 2^(level+2), level = l+3
        double area = side * side;
        for (int ri = 0; ri < 3; ++ri) {
            double ah = sqrt(area / ratios[ri]);
            double aw = area / ah;
            for (int si = 0; si < 3; ++si) {
                double s = pow(2.0, (double)si / 3.0);
                dims.d[(l * 9 + ri * 3 + si) * 2 + 0] = (float)(s * aw);
                dims.d[(l * 9 + ri * 3 + si) * 2 + 1] = (float)(s * ah);
            }
        }
    }

    decode_kernel<<<(NB * NA + 255) / 256, 256, 0, stream>>>(pred, boxes, dims);
    topk_kernel<<<NB * NCLS, 1024, 0, stream>>>(pred, top_idx, top_score);
    nms_kernel<<<NB * NCLS, 256, 0, stream>>>(boxes, top_idx, top_score, col_boxes, col_scores);
    combine_kernel<<<NB, 256, 0, stream>>>(col_boxes, col_scores, out);
}

// Round 2
// 596.521 us; speedup vs baseline: 3.1999x; 3.1999x over previous
//
#include <hip/hip_runtime.h>
#include <cmath>

#define NA 76725
#define NCLS 80
#define NB 4
#define KC 512
#define MPC 100
#define MT 100
#define TT 128          // anchors per transpose tile
#define NTILE 600       // ceil(NA/TT)
#define PADN 76800      // NA padded to multiple of 1024 (and 4)

struct Dims { float d[5 * 9 * 2]; };

// ---- helpers -------------------------------------------------------------

__device__ __forceinline__ unsigned keyof(float x) {
    unsigned u = __float_as_uint(x);
    return u ^ ((u & 0x80000000u) ? 0xFFFFFFFFu : 0x80000000u);
}
__device__ __forceinline__ float unkey(unsigned k) {
    unsigned u = (k & 0x80000000u) ? (k ^ 0x80000000u) : ~k;
    return __uint_as_float(u);
}
__device__ __forceinline__ float sigmoidf_dev(float x) {
    if (x >= 0.f) return 1.f / (1.f + expf(-x));
    float e = expf(x);
    return e / (1.f + e);
}

__device__ __forceinline__ float4 decode_box(float4 p, int a, const Dims& dims) {
    const int base[5] = {0, 57600, 72000, 75600, 76500};
    const int fw[5] = {80, 40, 20, 10, 5};
    const float strd[5] = {8.f, 16.f, 32.f, 64.f, 128.f};
    int l;
    if (a < 57600) l = 0;
    else if (a < 72000) l = 1;
    else if (a < 75600) l = 2;
    else if (a < 76500) l = 3;
    else l = 4;
    int i = a - base[l];
    int cell = i / 9, k = i - cell * 9;
    int x = cell % fw[l], y = cell / fw[l];
    float cx = ((float)x + 0.5f) * strd[l];
    float cy = ((float)y + 0.5f) * strd[l];
    float aw = dims.d[(l * 9 + k) * 2 + 0];
    float ah = dims.d[(l * 9 + k) * 2 + 1];
    float bx = __fmul_rn(p.x, 0.1f), by = __fmul_rn(p.y, 0.1f);
    float bw = __fmul_rn(p.z, 0.2f), bh = __fmul_rn(p.w, 0.2f);
    float4 o;
    o.x = __fadd_rn(__fmul_rn(bx, aw), cx);
    o.y = __fadd_rn(__fmul_rn(by, ah), cy);
    o.z = __fmul_rn(expf(bw), aw);
    o.w = __fmul_rn(expf(bh), ah);
    return o;
}

// ---- fast path kernel 1: fused transpose (to sort keys) + box decode -----

__global__ __launch_bounds__(256) void transpose_decode_kernel(const float* __restrict__ pred,
                                                               unsigned* __restrict__ keys,
                                                               float4* __restrict__ boxes, Dims dims) {
    __shared__ float tile[TT * 84];     // 43008 B
    const int blk = blockIdx.x;
    const int b = blk / NTILE, tix = blk - b * NTILE;
    const int t0 = tix * TT;
    int nrow = NA - t0; if (nrow > TT) nrow = TT;

    // contiguous tile load (rows are contiguous in pred), float4-vectorized
    const float4* src = reinterpret_cast<const float4*>(pred + ((size_t)b * NA + t0) * 84);
    const int nv = nrow * 21;
    for (int i = threadIdx.x; i < nv; i += 256)
        reinterpret_cast<float4*>(tile)[i] = src[i];
    __syncthreads();

    // transposed key writes: half-block per column, 128 contiguous elems each
    const int half = threadIdx.x >> 7;
    const int r = threadIdx.x & 127;
    const size_t colbase = (size_t)b * NCLS * PADN + (size_t)t0;
    for (int cc = 0; cc < 40; ++cc) {
        int c = cc * 2 + half;
        unsigned k = (r < nrow) ? keyof(tile[r * 84 + c]) : 0u;   // pads -> min key
        keys[colbase + (size_t)c * PADN + r] = k;
    }

    // box decode for this tile's anchors
    if (threadIdx.x < TT && r < nrow) {
        float4 p = *reinterpret_cast<const float4*>(&tile[r * 84 + 80]);
        boxes[(size_t)b * NA + t0 + r] = decode_box(p, t0 + r, dims);
    }
}

// ---- fast path kernel 2: per-column radix-select top-512 (12/12/8) -------

__global__ __launch_bounds__(1024) void topk2_kernel(const unsigned* __restrict__ keys,
                                                     int* __restrict__ top_idx,
                                                     float* __restrict__ top_score) {
    const int col = blockIdx.x;
    const int tid = threadIdx.x;
    const unsigned* colk = keys + (size_t)col * PADN;
    const uint4* kv = reinterpret_cast<const uint4*>(colk);

    __shared__ int hist[4096];
    __shared__ int partial[1024];
    __shared__ unsigned long long buf[KC];
    __shared__ int sh_bsel, sh_above, sh_ceq;
    __shared__ int gcount, eqtaken;
    __shared__ int wcnt[16];

    unsigned prefix = 0;
    int remaining = KC, ceq = 0;

    const int shifts[3] = {20, 8, 0};
    const int nbins[3] = {4096, 4096, 256};
    const unsigned masks[3] = {0u, 0xFFF00000u, 0xFFFFFF00u};

    for (int pass = 0; pass < 3; ++pass) {
        const int shift = shifts[pass];
        const int bins = nbins[pass];
        const unsigned mask_done = masks[pass];
        for (int i = tid; i < bins; i += 1024) hist[i] = 0;
        __syncthreads();
        for (int i = tid; i < PADN / 4; i += 1024) {
            uint4 k = kv[i];
            if ((k.x & mask_done) == prefix) atomicAdd(&hist[(k.x >> shift) & (bins - 1)], 1);
            if ((k.y & mask_done) == prefix) atomicAdd(&hist[(k.y >> shift) & (bins - 1)], 1);
            if ((k.z & mask_done) == prefix) atomicAdd(&hist[(k.z >> shift) & (bins - 1)], 1);
            if ((k.w & mask_done) == prefix) atomicAdd(&hist[(k.w >> shift) & (bins - 1)], 1);
        }
        __syncthreads();

        // parallel reversed (high->low) exclusive scan to find threshold bin
        const int nit = (bins + 1023) >> 10;   // 4 or 1 bins per thread
        int lsum = 0;
        for (int q = 0; q < nit; ++q) {
            int rr = tid * nit + q;
            if (rr < bins) lsum += hist[bins - 1 - rr];
        }
        partial[tid] = lsum;
        __syncthreads();
        int acc = lsum;
        for (int off = 1; off < 1024; off <<= 1) {
            int x = (tid >= off) ? partial[tid - off] : 0;
            __syncthreads();
            acc += x;
            partial[tid] = acc;
            __syncthreads();
        }
        int run = acc - lsum;   // exclusive base = count strictly above my first bin
        for (int q = 0; q < nit; ++q) {
            int rr = tid * nit + q;
            if (rr < bins) {
                int h = hist[bins - 1 - rr];
                if (run < remaining && remaining <= run + h) {
                    sh_bsel = bins - 1 - rr; sh_above = run; sh_ceq = h;
                }
                run += h;
            }
        }
        __syncthreads();
        prefix |= ((unsigned)sh_bsel) << shift;
        remaining -= sh_above;
        ceq = sh_ceq;
        __syncthreads();
    }

    const unsigned K = prefix;
    const int cgt = KC - remaining;
    const int need = remaining;
    if (tid == 0) { gcount = 0; eqtaken = 0; }
    __syncthreads();

    if (ceq == need) {
        // fast path: all ==K elements taken; order fixed by final sort
        for (int i = tid; i < PADN / 4; i += 1024) {
            uint4 k = kv[i];
            int a0 = i * 4;
            unsigned kk[4] = {k.x, k.y, k.z, k.w};
            #pragma unroll
            for (int j = 0; j < 4; ++j) {
                unsigned key = kk[j];
                int a = a0 + j;
                if (key > K) {
                    int p = atomicAdd(&gcount, 1);
                    buf[p] = ((unsigned long long)key << 32) | (unsigned long long)(0xFFFFFFFFu - (unsigned)a);
                } else if (key == K && a < NA) {
                    int p = atomicAdd(&eqtaken, 1);
                    buf[cgt + p] = ((unsigned long long)K << 32) | (unsigned long long)(0xFFFFFFFFu - (unsigned)a);
                }
            }
        }
        __syncthreads();
    } else {
        // slow path: smallest-index `need` among ==K via ordered block scan
        for (int bs = 0; bs < PADN; bs += 1024) {
            int a = bs + tid;
            unsigned key = colk[a];
            if (key > K) {
                int p = atomicAdd(&gcount, 1);
                buf[p] = ((unsigned long long)key << 32) | (unsigned long long)(0xFFFFFFFFu - (unsigned)a);
            }
            bool eq = (key == K) && (a < NA);
            unsigned long long m = __ballot(eq);
            int wave = tid >> 6, lane = tid & 63;
            if (lane == 0) wcnt[wave] = __popcll(m);
            __syncthreads();
            int off = eqtaken;
            for (int w = 0; w < wave; ++w) off += wcnt[w];
            int rank = off + __popcll(m & ((1ull << lane) - 1ull));
            if (eq && rank < need)
                buf[cgt + rank] = ((unsigned long long)K << 32) | (unsigned long long)(0xFFFFFFFFu - (unsigned)a);
            __syncthreads();
            if (tid == 0) {
                int s = 0;
                for (int w = 0; w < 16; ++w) s += wcnt[w];
                eqtaken += s;
            }
            __syncthreads();
        }
    }

    // bitonic sort 512 desc by (key desc, idx asc)
    for (int k2 = 2; k2 <= KC; k2 <<= 1) {
        for (int j = k2 >> 1; j > 0; j >>= 1) {
            __syncthreads();
            if (tid < KC) {
                int i = tid, ixj = i ^ j;
                if (ixj > i) {
                    unsigned long long A = buf[i], B = buf[ixj];
                    bool up = (i & k2) == 0;
                    if (up ? (A < B) : (A > B)) { buf[i] = B; buf[ixj] = A; }
                }
            }
        }
    }
    __syncthreads();
    if (tid < KC) {
        unsigned long long v = buf[tid];
        unsigned key = (unsigned)(v >> 32);
        int a = (int)(0xFFFFFFFFu - (unsigned)(v & 0xFFFFFFFFu));
        top_idx[col * KC + tid] = a;
        top_score[col * KC + tid] = sigmoidf_dev(unkey(key));
    }
}

// ---- fallback kernels (round-1 path, used if ws too small) ---------------

__global__ __launch_bounds__(256) void decode_kernel(const float* __restrict__ pred,
                                                     float4* __restrict__ boxes, Dims dims) {
    int g = blockIdx.x * 256 + threadIdx.x;
    if (g >= NB * NA) return;
    int b = g / NA, a = g - b * NA;
    const float4 p = *reinterpret_cast<const float4*>(pred + (size_t)g * 84 + 80);
    boxes[g] = decode_box(p, a, dims);
    (void)b;
}

__global__ __launch_bounds__(1024) void topk_kernel(const float* __restrict__ pred,
                                                    int* __restrict__ top_idx,
                                                    float* __restrict__ top_score) {
    const int col = blockIdx.x;
    const int b = col / NCLS, c = col - b * NCLS;
    const float* colp = pred + (size_t)b * NA * 84 + c;
    const int tid = threadIdx.x;

    __shared__ int hist[256];
    __shared__ unsigned long long buf[KC];
    __shared__ int sh_bsel, sh_above, sh_ceq;
    __shared__ int gcount, eqtaken;
    __shared__ int wcnt[16];

    unsigned prefix = 0;
    int remaining = KC, ceq = 0;

    for (int pass = 0; pass < 4; ++pass) {
        int shift = 24 - 8 * pass;
        unsigned mask_done = (pass == 0) ? 0u : (0xFFFFFFFFu << (shift + 8));
        if (tid < 256) hist[tid] = 0;
        __syncthreads();
        for (int a = tid; a < NA; a += 1024) {
            unsigned key = keyof(colp[(size_t)a * 84]);
            if ((key & mask_done) == prefix)
                atomicAdd(&hist[(key >> shift) & 0xFF], 1);
        }
        __syncthreads();
        if (tid == 0) {
            int cum = 0, bsel = 0, above = 0, cnt = 0;
            for (int bin = 255; bin >= 0; --bin) {
                int cc = hist[bin];
                if (cum + cc >= remaining) { bsel = bin; above = cum; cnt = cc; break; }
                cum += cc;
            }
            sh_bsel = bsel; sh_above = above; sh_ceq = cnt;
        }
        __syncthreads();
        prefix |= ((unsigned)sh_bsel) << shift;
        remaining -= sh_above;
        ceq = sh_ceq;
    }

    const unsigned K = prefix;
    const int cgt = KC - remaining;
    const int need = remaining;
    if (tid == 0) { gcount = 0; eqtaken = 0; }
    __syncthreads();

    if (ceq == need) {
        for (int a = tid; a < NA; a += 1024) {
            unsigned key = keyof(colp[(size_t)a * 84]);
            if (key > K) {
                int p = atomicAdd(&gcount, 1);
                buf[p] = ((unsigned long long)key << 32) | (unsigned long long)(0xFFFFFFFFu - (unsigned)a);
            } else if (key == K) {
                int p = atomicAdd(&eqtaken, 1);
                buf[cgt + p] = ((unsigned long long)K << 32) | (unsigned long long)(0xFFFFFFFFu - (unsigned)a);
            }
        }
        __syncthreads();
    } else {
        for (int bs = 0; bs < NA; bs += 1024) {
            int a = bs + tid;
            bool in = a < NA;
            unsigned key = in ? keyof(colp[(size_t)a * 84]) : 0u;
            if (in && key > K) {
                int p = atomicAdd(&gcount, 1);
                buf[p] = ((unsigned long long)key << 32) | (unsigned long long)(0xFFFFFFFFu - (unsigned)a);
            }
            bool eq = in && (key == K);
            unsigned long long m = __ballot(eq);
            int wave = tid >> 6, lane = tid & 63;
            if (lane == 0) wcnt[wave] = __popcll(m);
            __syncthreads();
            int off = eqtaken;
            for (int w = 0; w < wave; ++w) off += wcnt[w];
            int rank = off + __popcll(m & ((1ull << lane) - 1ull));
            if (eq && rank < need)
                buf[cgt + rank] = ((unsigned long long)K << 32) | (unsigned long long)(0xFFFFFFFFu - (unsigned)a);
            __syncthreads();
            if (tid == 0) {
                int s = 0;
                for (int w = 0; w < 16; ++w) s += wcnt[w];
                eqtaken += s;
            }
            __syncthreads();
        }
    }

    for (int k2 = 2; k2 <= KC; k2 <<= 1) {
        for (int j = k2 >> 1; j > 0; j >>= 1) {
            __syncthreads();
            if (tid < KC) {
                int i = tid, ixj = i ^ j;
                if (ixj > i) {
                    unsigned long long A = buf[i], B = buf[ixj];
                    bool up = (i & k2) == 0;
                    if (up ? (A < B) : (A > B)) { buf[i] = B; buf[ixj] = A; }
                }
            }
        }
    }
    __syncthreads();
    if (tid < KC) {
        unsigned long long v = buf[tid];
        unsigned key = (unsigned)(v >> 32);
        int a = (int)(0xFFFFFFFFu - (unsigned)(v & 0xFFFFFFFFu));
        top_idx[col * KC + tid] = a;
        top_score[col * KC + tid] = sigmoidf_dev(unkey(key));
    }
}

// ---- kernel 3: greedy NMS + first-100 compaction (unchanged) -------------

__global__ __launch_bounds__(256) void nms_kernel(const float4* __restrict__ boxes,
                                                  const int* __restrict__ top_idx,
                                                  const float* __restrict__ top_score,
                                                  float4* __restrict__ col_boxes,
                                                  float* __restrict__ col_scores) {
    const int col = blockIdx.x, b = col / NCLS;
    const int tid = threadIdx.x;
    __shared__ float y1[KC], x1[KC], y2[KC], x2[KC], ar[KC], sc[KC];
    __shared__ int keep[KC];
    __shared__ int sel[MPC];

    for (int t = tid; t < KC; t += 256) {
        int idx = top_idx[col * KC + t];
        float4 bx = boxes[(size_t)b * NA + idx];
        y1[t] = bx.x; x1[t] = bx.y; y2[t] = bx.z; x2[t] = bx.w;
        ar[t] = __fmul_rn(fmaxf(__fsub_rn(bx.z, bx.x), 0.f),
                          fmaxf(__fsub_rn(bx.w, bx.y), 0.f));
        float s = top_score[col * KC + t];
        sc[t] = s;
        keep[t] = (s > 0.05f) ? 1 : 0;
    }
    __syncthreads();

    for (int i = 0; i < KC; ++i) {
        if (keep[i]) {
            float Y1 = y1[i], X1 = x1[i], Y2 = y2[i], X2 = x2[i], AR = ar[i];
            for (int j = i + 1 + tid; j < KC; j += 256) {
                float ih = fmaxf(__fsub_rn(fminf(Y2, y2[j]), fmaxf(Y1, y1[j])), 0.f);
                float iw = fmaxf(__fsub_rn(fminf(X2, x2[j]), fmaxf(X1, x1[j])), 0.f);
                float inter = __fmul_rn(ih, iw);
                float uni = __fsub_rn(__fadd_rn(AR, ar[j]), inter);
                float iou = (uni > 0.f) ? __fdiv_rn(inter, uni) : 0.f;
                if (iou > 0.5f) keep[j] = 0;
            }
        }
        __syncthreads();
    }

    if (tid == 0) {
        int n = 0;
        for (int t = 0; t < KC && n < MPC; ++t) if (keep[t]) sel[n++] = t;
        for (int t = 0; t < KC && n < MPC; ++t) if (!keep[t]) sel[n++] = t;
    }
    __syncthreads();
    if (tid < MPC) {
        int t = sel[tid];
        col_scores[col * MPC + tid] = keep[t] ? sc[t] : 0.f;
        float4 o; o.x = y1[t]; o.y = x1[t]; o.z = y2[t]; o.w = x2[t];
        col_boxes[col * MPC + tid] = o;
    }
}

// ---- kernel 4: per-batch combine — LDS radix select top-100 of 8000 ------

__global__ __launch_bounds__(256) void combine_kernel(const float4* __restrict__ col_boxes,
                                                      const float* __restrict__ col_scores,
                                                      float* __restrict__ out) {
    const int b = blockIdx.x, tid = threadIdx.x;
    __shared__ unsigned long long buf[8192];   // 64 KiB: [0,8000) data, rest scratch
    int* hist = (int*)&buf[8000];              // 256 ints -> buf[8000..8127]
    int* bc = (int*)&buf[8128];                // 2 broadcast ints
    unsigned long long* cand = &buf[8000];     // 128 slots, reused after passes

    for (int t = tid; t < 8000; t += 256) {
        float s = col_scores[b * NCLS * MPC + t];
        buf[t] = ((unsigned long long)__float_as_uint(s) << 32) |
                 (unsigned long long)(0xFFFFFFFFu - (unsigned)t);
    }

    unsigned long long prefix = 0ull;
    int remaining = MT;
    for (int pass = 0; pass < 8; ++pass) {
        const int shift = 56 - 8 * pass;
        const unsigned long long mask_done = (pass == 0) ? 0ull : ((~0ull) << (shift + 8));
        __syncthreads();
        if (tid < 256) hist[tid] = 0;
        __syncthreads();
        for (int t = tid; t < 8000; t += 256) {
            unsigned long long k = buf[t];
            if ((k & mask_done) == prefix)
                atomicAdd(&hist[(int)((k >> shift) & 0xFF)], 1);
        }
        __syncthreads();
        if (tid == 0) {
            int cum = 0, bsel = 0, above = 0;
            for (int bin = 255; bin >= 0; --bin) {
                int cc = hist[bin];
                if (cum + cc >= remaining) { bsel = bin; above = cum; break; }
                cum += cc;
            }
            bc[0] = bsel; bc[1] = above;
        }
        __syncthreads();
        prefix |= ((unsigned long long)bc[0]) << shift;
        remaining -= bc[1];
    }
    // prefix is now the exact 100th-largest composite key (all keys unique)

    int* gcnt = (int*)&buf[8128];
    __syncthreads();
    if (tid == 0) *gcnt = 0;
    if (tid < 128) cand[tid] = 0ull;
    __syncthreads();
    for (int t = tid; t < 8000; t += 256) {
        unsigned long long k = buf[t];
        if (k >= prefix) { int p = atomicAdd(gcnt, 1); cand[p] = k; }   // exactly 100
    }
    __syncthreads();

    for (int k2 = 2; k2 <= 128; k2 <<= 1) {
        for (int j = k2 >> 1; j > 0; j >>= 1) {
            __syncthreads();
            if (tid < 128) {
                int i = tid, ixj = i ^ j;
                if (ixj > i) {
                    unsigned long long A = cand[i], B = cand[ixj];
                    bool up = (i & k2) == 0;
                    if (up ? (A < B) : (A > B)) { cand[i] = B; cand[ixj] = A; }
                }
            }
        }
    }
    __syncthreads();
    if (tid == 0) *gcnt = 0;
    __syncthreads();
    if (tid < MT) {
        unsigned long long v = cand[tid];
        float s = __uint_as_float((unsigned)(v >> 32));
        int f = (int)(0xFFFFFFFFu - (unsigned)(v & 0xFFFFFFFFu));
        bool valid = (s > 0.f);
        int cl = 0, p = 0;
        float4 bx = make_float4(0.f, 0.f, 0.f, 0.f);
        if (valid) {
            cl = f / MPC;
            p = f - cl * MPC;
            float4 raw = col_boxes[((size_t)b * NCLS + cl) * MPC + p];
            bx.x = fminf(fmaxf(raw.x, 0.f), 1.f);
            bx.y = fminf(fmaxf(raw.y, 0.f), 1.f);
            bx.z = fminf(fmaxf(raw.z, 0.f), 1.f);
            bx.w = fminf(fmaxf(raw.w, 0.f), 1.f);
            atomicAdd(gcnt, 1);
        }
        int o = b * MT + tid;
        out[o * 4 + 0] = bx.x;
        out[o * 4 + 1] = bx.y;
        out[o * 4 + 2] = bx.z;
        out[o * 4 + 3] = bx.w;
        out[NB * MT * 4 + o] = valid ? s : 0.f;
        out[NB * MT * 5 + o] = valid ? (float)cl : 0.f;
    }
    __syncthreads();
    if (tid == 0) out[NB * MT * 6 + b] = (float)(*gcnt);
}

// ---- launch --------------------------------------------------------------

extern "C" void kernel_launch(void* const* d_in, const int* in_sizes, int n_in,
                              void* d_out, int out_size, void* d_ws, size_t ws_size,
                              hipStream_t stream) {
    const float* pred = (const float*)d_in[1];
    float* out = (float*)d_out;
    char* ws = (char*)d_ws;

    // anchor dims computed in float64 exactly like the numpy reference
    Dims dims;
    const double ratios[3] = {0.5, 1.0, 2.0};
    for (int l = 0; l < 5; ++l) {
        double side = (double)(1 << (l + 5));
        double area = side * side;
        for (int ri = 0; ri < 3; ++ri) {
            double ah = sqrt(area / ratios[ri]);
            double aw = area / ah;
            for (int si = 0; si < 3; ++si) {
                double s = pow(2.0, (double)si / 3.0);
                dims.d[(l * 9 + ri * 3 + si) * 2 + 0] = (float)(s * aw);
                dims.d[(l * 9 + ri * 3 + si) * 2 + 1] = (float)(s * ah);
            }
        }
    }

    const size_t SZ_BOXES = (size_t)NB * NA * 16;            // 4,910,400
    const size_t SZ_KEYS  = (size_t)NB * NCLS * PADN * 4;    // 98,304,000
    const size_t need_fast = SZ_BOXES + SZ_KEYS + 655360 + 655360 + 512000 + 128000;

    if (ws_size >= need_fast) {
        float4*   boxes      = (float4*)(ws);
        unsigned* keys       = (unsigned*)(ws + SZ_BOXES);
        int*      top_idx    = (int*)   (ws + SZ_BOXES + SZ_KEYS);
        float*    top_score  = (float*) (ws + SZ_BOXES + SZ_KEYS + 655360);
        float4*   col_boxes  = (float4*)(ws + SZ_BOXES + SZ_KEYS + 1310720);
        float*    col_scores = (float*) (ws + SZ_BOXES + SZ_KEYS + 1822720);

        transpose_decode_kernel<<<NB * NTILE, 256, 0, stream>>>(pred, keys, boxes, dims);
        topk2_kernel<<<NB * NCLS, 1024, 0, stream>>>(keys, top_idx, top_score);
        nms_kernel<<<NB * NCLS, 256, 0, stream>>>(boxes, top_idx, top_score, col_boxes, col_scores);
        combine_kernel<<<NB, 256, 0, stream>>>(col_boxes, col_scores, out);
    } else {
        float4* boxes      = (float4*)(ws);
        int*    top_idx    = (int*)  (ws + 4910400);
        float*  top_score  = (float*)(ws + 5565760);
        float4* col_boxes  = (float4*)(ws + 6221120);
        float*  col_scores = (float*)(ws + 6733120);

        decode_kernel<<<(NB * NA + 255) / 256, 256, 0, stream>>>(pred, boxes, dims);
        topk_kernel<<<NB * NCLS, 1024, 0, stream>>>(pred, top_idx, top_score);
        nms_kernel<<<NB * NCLS, 256, 0, stream>>>(boxes, top_idx, top_score, col_boxes, col_scores);
        combine_kernel<<<NB, 256, 0, stream>>>(col_boxes, col_scores, out);
    }
}

// Round 3
// 536.890 us; speedup vs baseline: 3.5553x; 1.1111x over previous
//
#include <hip/hip_runtime.h>
#include <cmath>

#define NA 76725
#define NCLS 80
#define NB 4
#define KC 512
#define MPC 100
#define MT 100
#define TT 128          // anchors per transpose tile
#define NTILE 600       // ceil(NA/TT)
#define PADN 76800      // NA padded to multiple of 1024 (and 4)
#define CAP 4096        // candidate cap for single-histogram top-k fast path

struct Dims { float d[5 * 9 * 2]; };

// ---- helpers -------------------------------------------------------------

__device__ __forceinline__ unsigned keyof(float x) {
    unsigned u = __float_as_uint(x);
    return u ^ ((u & 0x80000000u) ? 0xFFFFFFFFu : 0x80000000u);
}
__device__ __forceinline__ float unkey(unsigned k) {
    unsigned u = (k & 0x80000000u) ? (k ^ 0x80000000u) : ~k;
    return __uint_as_float(u);
}
__device__ __forceinline__ float sigmoidf_dev(float x) {
    if (x >= 0.f) return 1.f / (1.f + expf(-x));
    float e = expf(x);
    return e / (1.f + e);
}
__device__ __forceinline__ unsigned long long compose(unsigned key, int a) {
    return ((unsigned long long)key << 32) | (unsigned long long)(0xFFFFFFFFu - (unsigned)a);
}

__device__ __forceinline__ float4 decode_box(float4 p, int a, const Dims& dims) {
    const int base[5] = {0, 57600, 72000, 75600, 76500};
    const int fw[5] = {80, 40, 20, 10, 5};
    const float strd[5] = {8.f, 16.f, 32.f, 64.f, 128.f};
    int l;
    if (a < 57600) l = 0;
    else if (a < 72000) l = 1;
    else if (a < 75600) l = 2;
    else if (a < 76500) l = 3;
    else l = 4;
    int i = a - base[l];
    int cell = i / 9, k = i - cell * 9;
    int x = cell % fw[l], y = cell / fw[l];
    float cx = ((float)x + 0.5f) * strd[l];
    float cy = ((float)y + 0.5f) * strd[l];
    float aw = dims.d[(l * 9 + k) * 2 + 0];
    float ah = dims.d[(l * 9 + k) * 2 + 1];
    float bx = __fmul_rn(p.x, 0.1f), by = __fmul_rn(p.y, 0.1f);
    float bw = __fmul_rn(p.z, 0.2f), bh = __fmul_rn(p.w, 0.2f);
    float4 o;
    o.x = __fadd_rn(__fmul_rn(bx, aw), cx);
    o.y = __fadd_rn(__fmul_rn(by, ah), cy);
    o.z = __fmul_rn(expf(bw), aw);
    o.w = __fmul_rn(expf(bh), ah);
    return o;
}

// ---- kernel 1: fused transpose (to sort keys) + box decode ---------------

__global__ __launch_bounds__(256) void transpose_decode_kernel(const float* __restrict__ pred,
                                                               unsigned* __restrict__ keys,
                                                               float4* __restrict__ boxes, Dims dims) {
    __shared__ float tile[TT * 84];     // 43008 B
    const int blk = blockIdx.x;
    const int b = blk / NTILE, tix = blk - b * NTILE;
    const int t0 = tix * TT;
    int nrow = NA - t0; if (nrow > TT) nrow = TT;

    const float4* src = reinterpret_cast<const float4*>(pred + ((size_t)b * NA + t0) * 84);
    const int nv = nrow * 21;
    for (int i = threadIdx.x; i < nv; i += 256)
        reinterpret_cast<float4*>(tile)[i] = src[i];
    __syncthreads();

    const int half = threadIdx.x >> 7;
    const int r = threadIdx.x & 127;
    const size_t colbase = (size_t)b * NCLS * PADN + (size_t)t0;
    for (int cc = 0; cc < 40; ++cc) {
        int c = cc * 2 + half;
        unsigned k = (r < nrow) ? keyof(tile[r * 84 + c]) : 0u;   // pads -> min key
        keys[colbase + (size_t)c * PADN + r] = k;
    }

    if (threadIdx.x < TT && r < nrow) {
        float4 p = *reinterpret_cast<const float4*>(&tile[r * 84 + 80]);
        boxes[(size_t)b * NA + t0 + r] = decode_box(p, t0 + r, dims);
    }
}

// ---- per-block reversed (high->low) histogram threshold find -------------
// all threads must call; sh3 = {bsel, above(count strictly above bin), count-in-bin}

__device__ void find_bin(int* hist, int* partial, int bins, int remaining, int* sh3) {
    const int tid = threadIdx.x;
    const int nit = (bins + 1023) >> 10;
    int lsum = 0;
    for (int q = 0; q < nit; ++q) {
        int rr = tid * nit + q;
        if (rr < bins) lsum += hist[bins - 1 - rr];
    }
    partial[tid] = lsum;
    __syncthreads();
    int acc = lsum;
    for (int off = 1; off < 1024; off <<= 1) {
        int x = (tid >= off) ? partial[tid - off] : 0;
        __syncthreads();
        acc += x;
        partial[tid] = acc;
        __syncthreads();
    }
    int run = acc - lsum;
    for (int q = 0; q < nit; ++q) {
        int rr = tid * nit + q;
        if (rr < bins) {
            int h = hist[bins - 1 - rr];
            if (run < remaining && remaining <= run + h) { sh3[0] = bins - 1 - rr; sh3[1] = run; sh3[2] = h; }
            run += h;
        }
    }
    __syncthreads();
}

// ---- kernel 2: per-column top-512 ----------------------------------------
// fast path: 1 histogram sweep + 1 collect sweep + in-LDS exact select

__global__ __launch_bounds__(1024) void topk2_kernel(const unsigned* __restrict__ keys,
                                                     int* __restrict__ top_idx,
                                                     float* __restrict__ top_score) {
    const int col = blockIdx.x;
    const int tid = threadIdx.x;
    const unsigned* colk = keys + (size_t)col * PADN;
    const uint4* kv = reinterpret_cast<const uint4*>(colk);

    __shared__ int hist[4096];
    __shared__ int partial[1024];
    __shared__ unsigned long long cand[CAP];
    __shared__ unsigned long long buf[KC];
    __shared__ int sh3[3];
    __shared__ int gcount, eqtaken;
    __shared__ int wcnt[16];

    // ---- pass 1: 12-bit coarse histogram over all keys
    for (int i = tid; i < 4096; i += 1024) hist[i] = 0;
    __syncthreads();
    for (int i = tid; i < PADN / 4; i += 1024) {
        uint4 k = kv[i];
        atomicAdd(&hist[k.x >> 20], 1);
        atomicAdd(&hist[k.y >> 20], 1);
        atomicAdd(&hist[k.z >> 20], 1);
        atomicAdd(&hist[k.w >> 20], 1);
    }
    __syncthreads();
    find_bin(hist, partial, 4096, KC, sh3);
    const int bsel = sh3[0], above = sh3[1], ceq1 = sh3[2];
    const int ncand = above + ceq1;

    if (ncand <= CAP) {
        // ---- fast path: collect all candidates (key >= bin floor), exact select in LDS
        // bsel >= 1 here (bsel==0 forces ncand ~ 76800 > CAP), so pads (key 0) excluded.
        const unsigned fk = ((unsigned)bsel) << 20;
        if (tid == 0) gcount = 0;
        __syncthreads();
        for (int i = tid; i < PADN / 4; i += 1024) {
            uint4 k = kv[i];
            int a0 = i * 4;
            if (k.x >= fk) { int p = atomicAdd(&gcount, 1); cand[p] = compose(k.x, a0 + 0); }
            if (k.y >= fk) { int p = atomicAdd(&gcount, 1); cand[p] = compose(k.y, a0 + 1); }
            if (k.z >= fk) { int p = atomicAdd(&gcount, 1); cand[p] = compose(k.z, a0 + 2); }
            if (k.w >= fk) { int p = atomicAdd(&gcount, 1); cand[p] = compose(k.w, a0 + 3); }
        }
        __syncthreads();
        const int nc = gcount;   // == ncand, >= 512

        // exact 512th-largest composite via 8x8-bit radix (composites unique)
        unsigned long long cpre = 0ull;
        int rem512 = KC;
        for (int pass = 0; pass < 8; ++pass) {
            const int shift = 56 - 8 * pass;
            const unsigned long long mdone = pass ? ((~0ull) << (shift + 8)) : 0ull;
            if (tid < 256) hist[tid] = 0;
            __syncthreads();
            for (int t = tid; t < nc; t += 1024) {
                unsigned long long k = cand[t];
                if ((k & mdone) == cpre) atomicAdd(&hist[(int)((k >> shift) & 255)], 1);
            }
            __syncthreads();
            find_bin(hist, partial, 256, rem512, sh3);
            cpre |= ((unsigned long long)(unsigned)sh3[0]) << shift;
            rem512 -= sh3[1];
            __syncthreads();
        }
        // collect exactly 512 composites >= cpre
        if (tid == 0) gcount = 0;
        __syncthreads();
        for (int t = tid; t < nc; t += 1024) {
            unsigned long long k = cand[t];
            if (k >= cpre) { int p = atomicAdd(&gcount, 1); buf[p] = k; }
        }
        __syncthreads();
    } else {
        // ---- fallback: original 3-pass radix over the key array
        unsigned prefix = ((unsigned)bsel) << 20;
        int remaining = KC - above;
        int ceqf = ceq1;

        // pass 2: shift 8, 4096 bins
        for (int i = tid; i < 4096; i += 1024) hist[i] = 0;
        __syncthreads();
        for (int i = tid; i < PADN / 4; i += 1024) {
            uint4 k = kv[i];
            if ((k.x & 0xFFF00000u) == prefix) atomicAdd(&hist[(k.x >> 8) & 4095], 1);
            if ((k.y & 0xFFF00000u) == prefix) atomicAdd(&hist[(k.y >> 8) & 4095], 1);
            if ((k.z & 0xFFF00000u) == prefix) atomicAdd(&hist[(k.z >> 8) & 4095], 1);
            if ((k.w & 0xFFF00000u) == prefix) atomicAdd(&hist[(k.w >> 8) & 4095], 1);
        }
        __syncthreads();
        find_bin(hist, partial, 4096, remaining, sh3);
        prefix |= ((unsigned)sh3[0]) << 8;
        remaining -= sh3[1];
        ceqf = sh3[2];

        // pass 3: shift 0, 256 bins
        if (tid < 256) hist[tid] = 0;
        __syncthreads();
        for (int i = tid; i < PADN / 4; i += 1024) {
            uint4 k = kv[i];
            if ((k.x & 0xFFFFFF00u) == prefix) atomicAdd(&hist[k.x & 255], 1);
            if ((k.y & 0xFFFFFF00u) == prefix) atomicAdd(&hist[k.y & 255], 1);
            if ((k.z & 0xFFFFFF00u) == prefix) atomicAdd(&hist[k.z & 255], 1);
            if ((k.w & 0xFFFFFF00u) == prefix) atomicAdd(&hist[k.w & 255], 1);
        }
        __syncthreads();
        find_bin(hist, partial, 256, remaining, sh3);
        prefix |= (unsigned)sh3[0];
        remaining -= sh3[1];
        ceqf = sh3[2];

        const unsigned K = prefix;
        const int cgt = KC - remaining;
        const int need = remaining;
        if (tid == 0) { gcount = 0; eqtaken = 0; }
        __syncthreads();

        if (ceqf == need) {
            for (int i = tid; i < PADN / 4; i += 1024) {
                uint4 k = kv[i];
                int a0 = i * 4;
                unsigned kk[4] = {k.x, k.y, k.z, k.w};
                #pragma unroll
                for (int j = 0; j < 4; ++j) {
                    unsigned key = kk[j];
                    int a = a0 + j;
                    if (key > K) {
                        int p = atomicAdd(&gcount, 1);
                        buf[p] = compose(key, a);
                    } else if (key == K && a < NA) {
                        int p = atomicAdd(&eqtaken, 1);
                        buf[cgt + p] = compose(K, a);
                    }
                }
            }
            __syncthreads();
        } else {
            for (int bs = 0; bs < PADN; bs += 1024) {
                int a = bs + tid;
                unsigned key = colk[a];
                if (key > K) {
                    int p = atomicAdd(&gcount, 1);
                    buf[p] = compose(key, a);
                }
                bool eq = (key == K) && (a < NA);
                unsigned long long m = __ballot(eq);
                int wave = tid >> 6, lane = tid & 63;
                if (lane == 0) wcnt[wave] = __popcll(m);
                __syncthreads();
                int off = eqtaken;
                for (int w = 0; w < wave; ++w) off += wcnt[w];
                int rank = off + __popcll(m & ((1ull << lane) - 1ull));
                if (eq && rank < need)
                    buf[cgt + rank] = compose(K, a);
                __syncthreads();
                if (tid == 0) {
                    int s = 0;
                    for (int w = 0; w < 16; ++w) s += wcnt[w];
                    eqtaken += s;
                }
                __syncthreads();
            }
        }
    }

    // ---- common epilogue: bitonic sort 512 desc by composite, write out
    for (int k2 = 2; k2 <= KC; k2 <<= 1) {
        for (int j = k2 >> 1; j > 0; j >>= 1) {
            __syncthreads();
            if (tid < KC) {
                int i = tid, ixj = i ^ j;
                if (ixj > i) {
                    unsigned long long A = buf[i], B = buf[ixj];
                    bool up = (i & k2) == 0;
                    if (up ? (A < B) : (A > B)) { buf[i] = B; buf[ixj] = A; }
                }
            }
        }
    }
    __syncthreads();
    if (tid < KC) {
        unsigned long long v = buf[tid];
        unsigned key = (unsigned)(v >> 32);
        int a = (int)(0xFFFFFFFFu - (unsigned)(v & 0xFFFFFFFFu));
        top_idx[col * KC + tid] = a;
        top_score[col * KC + tid] = sigmoidf_dev(unkey(key));
    }
}

// ---- kernel 3: bitmask NMS -----------------------------------------------

__global__ __launch_bounds__(256) void nms_kernel(const float4* __restrict__ boxes,
                                                  const int* __restrict__ top_idx,
                                                  const float* __restrict__ top_score,
                                                  float4* __restrict__ col_boxes,
                                                  float* __restrict__ col_scores) {
    const int col = blockIdx.x, b = col / NCLS;
    const int tid = threadIdx.x;
    const int wave = tid >> 6, lane = tid & 63;
    __shared__ float y1[KC], x1[KC], y2[KC], x2[KC], ar[KC], sc[KC];
    __shared__ unsigned long long maskrow[KC * 8];   // 32 KiB suppression bit-matrix
    __shared__ unsigned long long keep0w[8], keepw[8];
    __shared__ int sel[MPC];

    for (int t = tid; t < KC; t += 256) {
        int idx = top_idx[col * KC + t];
        float4 bx = boxes[(size_t)b * NA + idx];
        y1[t] = bx.x; x1[t] = bx.y; y2[t] = bx.z; x2[t] = bx.w;
        ar[t] = __fmul_rn(fmaxf(__fsub_rn(bx.z, bx.x), 0.f),
                          fmaxf(__fsub_rn(bx.w, bx.y), 0.f));
        float s = top_score[col * KC + t];
        sc[t] = s;
        unsigned long long m = __ballot(s > 0.05f);
        if (lane == 0) keep0w[t >> 6] = m;
    }
    __syncthreads();

    // build: maskrow[i][wd] bit j-in-word set iff iou(i, wd*64+lane) > 0.5 and j > i
    for (int wd = 0; wd < 8; ++wd) {
        const int j = (wd << 6) + lane;
        const float jy1 = y1[j], jx1 = x1[j], jy2 = y2[j], jx2 = x2[j], jar = ar[j];
        for (int i = wave; i < KC; i += 4) {
            unsigned long long m = 0ull;
            if (((wd << 6) + 63) > i) {                 // word has some j > i
                float ih = fmaxf(__fsub_rn(fminf(y2[i], jy2), fmaxf(y1[i], jy1)), 0.f);
                float iw = fmaxf(__fsub_rn(fminf(x2[i], jx2), fmaxf(x1[i], jx1)), 0.f);
                float inter = __fmul_rn(ih, iw);
                float uni = __fsub_rn(__fadd_rn(ar[i], jar), inter);
                float iou = (uni > 0.f) ? __fdiv_rn(inter, uni) : 0.f;
                m = __ballot(iou > 0.5f && j > i);
            }
            if (lane == 0) maskrow[i * 8 + wd] = m;
        }
    }
    __syncthreads();

    // greedy resolution: register-resident, unconditional loads (no dependent LDS chain)
    if (tid == 0) {
        unsigned long long rem[8] = {0, 0, 0, 0, 0, 0, 0, 0};
        #pragma unroll
        for (int W = 0; W < 8; ++W) {
            const unsigned long long kw = keep0w[W];
            for (int t = 0; t < 64; ++t) {
                const int i = (W << 6) + t;
                const unsigned long long am = 0ull - (((kw & ~rem[W]) >> t) & 1ull);
                const unsigned long long* row = &maskrow[i * 8];
                #pragma unroll
                for (int w2 = W; w2 < 8; ++w2) rem[w2] |= row[w2] & am;
            }
        }
        #pragma unroll
        for (int w = 0; w < 8; ++w) keepw[w] = keep0w[w] & ~rem[w];
        int n = 0;
        for (int t = 0; t < KC && n < MPC; ++t) if ((keepw[t >> 6] >> (t & 63)) & 1) sel[n++] = t;
        for (int t = 0; t < KC && n < MPC; ++t) if (!((keepw[t >> 6] >> (t & 63)) & 1)) sel[n++] = t;
    }
    __syncthreads();
    if (tid < MPC) {
        int t = sel[tid];
        bool kp = (keepw[t >> 6] >> (t & 63)) & 1;
        col_scores[col * MPC + tid] = kp ? sc[t] : 0.f;
        float4 o; o.x = y1[t]; o.y = x1[t]; o.z = y2[t]; o.w = x2[t];
        col_boxes[col * MPC + tid] = o;
    }
}

// ---- kernel 4: per-batch combine — LDS radix select top-100 of 8000 ------

__global__ __launch_bounds__(256) void combine_kernel(const float4* __restrict__ col_boxes,
                                                      const float* __restrict__ col_scores,
                                                      float* __restrict__ out) {
    const int b = blockIdx.x, tid = threadIdx.x;
    __shared__ unsigned long long buf[8192];   // 64 KiB: [0,8000) data, rest scratch
    int* hist = (int*)&buf[8000];
    int* bc = (int*)&buf[8128];
    unsigned long long* cand = &buf[8000];

    for (int t = tid; t < 8000; t += 256) {
        float s = col_scores[b * NCLS * MPC + t];
        buf[t] = ((unsigned long long)__float_as_uint(s) << 32) |
                 (unsigned long long)(0xFFFFFFFFu - (unsigned)t);
    }

    unsigned long long prefix = 0ull;
    int remaining = MT;
    for (int pass = 0; pass < 8; ++pass) {
        const int shift = 56 - 8 * pass;
        const unsigned long long mask_done = (pass == 0) ? 0ull : ((~0ull) << (shift + 8));
        __syncthreads();
        if (tid < 256) hist[tid] = 0;
        __syncthreads();
        for (int t = tid; t < 8000; t += 256) {
            unsigned long long k = buf[t];
            if ((k & mask_done) == prefix)
                atomicAdd(&hist[(int)((k >> shift) & 0xFF)], 1);
        }
        __syncthreads();
        if (tid == 0) {
            int cum = 0, bsel = 0, above = 0;
            for (int bin = 255; bin >= 0; --bin) {
                int cc = hist[bin];
                if (cum + cc >= remaining) { bsel = bin; above = cum; break; }
                cum += cc;
            }
            bc[0] = bsel; bc[1] = above;
        }
        __syncthreads();
        prefix |= ((unsigned long long)bc[0]) << shift;
        remaining -= bc[1];
    }

    int* gcnt = (int*)&buf[8128];
    __syncthreads();
    if (tid == 0) *gcnt = 0;
    if (tid < 128) cand[tid] = 0ull;
    __syncthreads();
    for (int t = tid; t < 8000; t += 256) {
        unsigned long long k = buf[t];
        if (k >= prefix) { int p = atomicAdd(gcnt, 1); cand[p] = k; }   // exactly 100
    }
    __syncthreads();

    for (int k2 = 2; k2 <= 128; k2 <<= 1) {
        for (int j = k2 >> 1; j > 0; j >>= 1) {
            __syncthreads();
            if (tid < 128) {
                int i = tid, ixj = i ^ j;
                if (ixj > i) {
                    unsigned long long A = cand[i], B = cand[ixj];
                    bool up = (i & k2) == 0;
                    if (up ? (A < B) : (A > B)) { cand[i] = B; cand[ixj] = A; }
                }
            }
        }
    }
    __syncthreads();
    if (tid == 0) *gcnt = 0;
    __syncthreads();
    if (tid < MT) {
        unsigned long long v = cand[tid];
        float s = __uint_as_float((unsigned)(v >> 32));
        int f = (int)(0xFFFFFFFFu - (unsigned)(v & 0xFFFFFFFFu));
        bool valid = (s > 0.f);
        int cl = 0, p = 0;
        float4 bx = make_float4(0.f, 0.f, 0.f, 0.f);
        if (valid) {
            cl = f / MPC;
            p = f - cl * MPC;
            float4 raw = col_boxes[((size_t)b * NCLS + cl) * MPC + p];
            bx.x = fminf(fmaxf(raw.x, 0.f), 1.f);
            bx.y = fminf(fmaxf(raw.y, 0.f), 1.f);
            bx.z = fminf(fmaxf(raw.z, 0.f), 1.f);
            bx.w = fminf(fmaxf(raw.w, 0.f), 1.f);
            atomicAdd(gcnt, 1);
        }
        int o = b * MT + tid;
        out[o * 4 + 0] = bx.x;
        out[o * 4 + 1] = bx.y;
        out[o * 4 + 2] = bx.z;
        out[o * 4 + 3] = bx.w;
        out[NB * MT * 4 + o] = valid ? s : 0.f;
        out[NB * MT * 5 + o] = valid ? (float)cl : 0.f;
    }
    __syncthreads();
    if (tid == 0) out[NB * MT * 6 + b] = (float)(*gcnt);
}

// ---- launch --------------------------------------------------------------

extern "C" void kernel_launch(void* const* d_in, const int* in_sizes, int n_in,
                              void* d_out, int out_size, void* d_ws, size_t ws_size,
                              hipStream_t stream) {
    const float* pred = (const float*)d_in[1];
    float* out = (float*)d_out;
    char* ws = (char*)d_ws;

    Dims dims;
    const double ratios[3] = {0.5, 1.0, 2.0};
    for (int l = 0; l < 5; ++l) {
        double side = (double)(1 << (l + 5));
        double area = side * side;
        for (int ri = 0; ri < 3; ++ri) {
            double ah = sqrt(area / ratios[ri]);
            double aw = area / ah;
            for (int si = 0; si < 3; ++si) {
                double s = pow(2.0, (double)si / 3.0);
                dims.d[(l * 9 + ri * 3 + si) * 2 + 0] = (float)(s * aw);
                dims.d[(l * 9 + ri * 3 + si) * 2 + 1] = (float)(s * ah);
            }
        }
    }

    const size_t SZ_BOXES = (size_t)NB * NA * 16;            // 4,910,400
    const size_t SZ_KEYS  = (size_t)NB * NCLS * PADN * 4;    // 98,304,000

    float4*   boxes      = (float4*)(ws);
    unsigned* keys       = (unsigned*)(ws + SZ_BOXES);
    int*      top_idx    = (int*)   (ws + SZ_BOXES + SZ_KEYS);
    float*    top_score  = (float*) (ws + SZ_BOXES + SZ_KEYS + 655360);
    float4*   col_boxes  = (float4*)(ws + SZ_BOXES + SZ_KEYS + 1310720);
    float*    col_scores = (float*) (ws + SZ_BOXES + SZ_KEYS + 1822720);

    transpose_decode_kernel<<<NB * NTILE, 256, 0, stream>>>(pred, keys, boxes, dims);
    topk2_kernel<<<NB * NCLS, 1024, 0, stream>>>(keys, top_idx, top_score);
    nms_kernel<<<NB * NCLS, 256, 0, stream>>>(boxes, top_idx, top_score, col_boxes, col_scores);
    combine_kernel<<<NB, 256, 0, stream>>>(col_boxes, col_scores, out);
}

// Round 4
// 476.546 us; speedup vs baseline: 4.0055x; 1.1266x over previous
//
#include <hip/hip_runtime.h>
#include <cmath>

#define NA 76725
#define NCLS 80
#define NB 4
#define KC 512
#define MPC 100
#define MT 100
#define TT 128          // anchors per transpose tile
#define NTILE 600       // ceil(NA/TT)
#define PADN 76800      // NA padded to multiple of 1024 (and 4)
#define CAP 4096        // candidate cap for single-histogram top-k fast path

struct Dims { float d[5 * 9 * 2]; };

// ---- helpers -------------------------------------------------------------

__device__ __forceinline__ unsigned keyof(float x) {
    unsigned u = __float_as_uint(x);
    return u ^ ((u & 0x80000000u) ? 0xFFFFFFFFu : 0x80000000u);
}
__device__ __forceinline__ float unkey(unsigned k) {
    unsigned u = (k & 0x80000000u) ? (k ^ 0x80000000u) : ~k;
    return __uint_as_float(u);
}
__device__ __forceinline__ float sigmoidf_dev(float x) {
    if (x >= 0.f) return 1.f / (1.f + expf(-x));
    float e = expf(x);
    return e / (1.f + e);
}
__device__ __forceinline__ unsigned long long compose(unsigned key, int a) {
    return ((unsigned long long)key << 32) | (unsigned long long)(0xFFFFFFFFu - (unsigned)a);
}

__device__ __forceinline__ float4 decode_box(float4 p, int a, const Dims& dims) {
    const int base[5] = {0, 57600, 72000, 75600, 76500};
    const int fw[5] = {80, 40, 20, 10, 5};
    const float strd[5] = {8.f, 16.f, 32.f, 64.f, 128.f};
    int l;
    if (a < 57600) l = 0;
    else if (a < 72000) l = 1;
    else if (a < 75600) l = 2;
    else if (a < 76500) l = 3;
    else l = 4;
    int i = a - base[l];
    int cell = i / 9, k = i - cell * 9;
    int x = cell % fw[l], y = cell / fw[l];
    float cx = ((float)x + 0.5f) * strd[l];
    float cy = ((float)y + 0.5f) * strd[l];
    float aw = dims.d[(l * 9 + k) * 2 + 0];
    float ah = dims.d[(l * 9 + k) * 2 + 1];
    float bx = __fmul_rn(p.x, 0.1f), by = __fmul_rn(p.y, 0.1f);
    float bw = __fmul_rn(p.z, 0.2f), bh = __fmul_rn(p.w, 0.2f);
    float4 o;
    o.x = __fadd_rn(__fmul_rn(bx, aw), cx);
    o.y = __fadd_rn(__fmul_rn(by, ah), cy);
    o.z = __fmul_rn(expf(bw), aw);
    o.w = __fmul_rn(expf(bh), ah);
    return o;
}

// ---- kernel 1: fused transpose (to sort keys) + box decode ---------------

__global__ __launch_bounds__(256) void transpose_decode_kernel(const float* __restrict__ pred,
                                                               unsigned* __restrict__ keys,
                                                               float4* __restrict__ boxes, Dims dims) {
    __shared__ float tile[TT * 84];     // 43008 B
    const int blk = blockIdx.x;
    const int b = blk / NTILE, tix = blk - b * NTILE;
    const int t0 = tix * TT;
    int nrow = NA - t0; if (nrow > TT) nrow = TT;

    const float4* src = reinterpret_cast<const float4*>(pred + ((size_t)b * NA + t0) * 84);
    const int nv = nrow * 21;
    for (int i = threadIdx.x; i < nv; i += 256)
        reinterpret_cast<float4*>(tile)[i] = src[i];
    __syncthreads();

    const int half = threadIdx.x >> 7;
    const int r = threadIdx.x & 127;
    const size_t colbase = (size_t)b * NCLS * PADN + (size_t)t0;
    for (int cc = 0; cc < 40; ++cc) {
        int c = cc * 2 + half;
        unsigned k = (r < nrow) ? keyof(tile[r * 84 + c]) : 0u;   // pads -> min key
        keys[colbase + (size_t)c * PADN + r] = k;
    }

    if (threadIdx.x < TT && r < nrow) {
        float4 p = *reinterpret_cast<const float4*>(&tile[r * 84 + 80]);
        boxes[(size_t)b * NA + t0 + r] = decode_box(p, t0 + r, dims);
    }
}

// ---- per-block reversed (high->low) histogram threshold find -------------

__device__ void find_bin(int* hist, int* partial, int bins, int remaining, int* sh3) {
    const int tid = threadIdx.x;
    const int nit = (bins + 1023) >> 10;
    int lsum = 0;
    for (int q = 0; q < nit; ++q) {
        int rr = tid * nit + q;
        if (rr < bins) lsum += hist[bins - 1 - rr];
    }
    partial[tid] = lsum;
    __syncthreads();
    int acc = lsum;
    for (int off = 1; off < 1024; off <<= 1) {
        int x = (tid >= off) ? partial[tid - off] : 0;
        __syncthreads();
        acc += x;
        partial[tid] = acc;
        __syncthreads();
    }
    int run = acc - lsum;
    for (int q = 0; q < nit; ++q) {
        int rr = tid * nit + q;
        if (rr < bins) {
            int h = hist[bins - 1 - rr];
            if (run < remaining && remaining <= run + h) { sh3[0] = bins - 1 - rr; sh3[1] = run; sh3[2] = h; }
            run += h;
        }
    }
    __syncthreads();
}

// ---- kernel 2: per-column top-512 ----------------------------------------

__global__ __launch_bounds__(1024) void topk2_kernel(const unsigned* __restrict__ keys,
                                                     int* __restrict__ top_idx,
                                                     float* __restrict__ top_score) {
    const int col = blockIdx.x;
    const int tid = threadIdx.x;
    const unsigned* colk = keys + (size_t)col * PADN;
    const uint4* kv = reinterpret_cast<const uint4*>(colk);

    __shared__ int hist[4096];
    __shared__ int partial[1024];
    __shared__ unsigned long long cand[CAP];
    __shared__ unsigned long long buf[KC];
    __shared__ int sh3[3];
    __shared__ int gcount, eqtaken;
    __shared__ int wcnt[16];

    // ---- pass 1: 12-bit coarse histogram over all keys
    for (int i = tid; i < 4096; i += 1024) hist[i] = 0;
    __syncthreads();
    for (int i = tid; i < PADN / 4; i += 1024) {
        uint4 k = kv[i];
        atomicAdd(&hist[k.x >> 20], 1);
        atomicAdd(&hist[k.y >> 20], 1);
        atomicAdd(&hist[k.z >> 20], 1);
        atomicAdd(&hist[k.w >> 20], 1);
    }
    __syncthreads();
    find_bin(hist, partial, 4096, KC, sh3);
    const int bsel = sh3[0], above = sh3[1], ceq1 = sh3[2];
    const int ncand = above + ceq1;

    if (ncand <= CAP) {
        const unsigned fk = ((unsigned)bsel) << 20;
        if (tid == 0) gcount = 0;
        __syncthreads();
        for (int i = tid; i < PADN / 4; i += 1024) {
            uint4 k = kv[i];
            int a0 = i * 4;
            if (k.x >= fk) { int p = atomicAdd(&gcount, 1); cand[p] = compose(k.x, a0 + 0); }
            if (k.y >= fk) { int p = atomicAdd(&gcount, 1); cand[p] = compose(k.y, a0 + 1); }
            if (k.z >= fk) { int p = atomicAdd(&gcount, 1); cand[p] = compose(k.z, a0 + 2); }
            if (k.w >= fk) { int p = atomicAdd(&gcount, 1); cand[p] = compose(k.w, a0 + 3); }
        }
        __syncthreads();
        const int nc = gcount;

        unsigned long long cpre = 0ull;
        int rem512 = KC;
        for (int pass = 0; pass < 8; ++pass) {
            const int shift = 56 - 8 * pass;
            const unsigned long long mdone = pass ? ((~0ull) << (shift + 8)) : 0ull;
            if (tid < 256) hist[tid] = 0;
            __syncthreads();
            for (int t = tid; t < nc; t += 1024) {
                unsigned long long k = cand[t];
                if ((k & mdone) == cpre) atomicAdd(&hist[(int)((k >> shift) & 255)], 1);
            }
            __syncthreads();
            find_bin(hist, partial, 256, rem512, sh3);
            cpre |= ((unsigned long long)(unsigned)sh3[0]) << shift;
            rem512 -= sh3[1];
            __syncthreads();
        }
        if (tid == 0) gcount = 0;
        __syncthreads();
        for (int t = tid; t < nc; t += 1024) {
            unsigned long long k = cand[t];
            if (k >= cpre) { int p = atomicAdd(&gcount, 1); buf[p] = k; }
        }
        __syncthreads();
    } else {
        unsigned prefix = ((unsigned)bsel) << 20;
        int remaining = KC - above;
        int ceqf = ceq1;

        for (int i = tid; i < 4096; i += 1024) hist[i] = 0;
        __syncthreads();
        for (int i = tid; i < PADN / 4; i += 1024) {
            uint4 k = kv[i];
            if ((k.x & 0xFFF00000u) == prefix) atomicAdd(&hist[(k.x >> 8) & 4095], 1);
            if ((k.y & 0xFFF00000u) == prefix) atomicAdd(&hist[(k.y >> 8) & 4095], 1);
            if ((k.z & 0xFFF00000u) == prefix) atomicAdd(&hist[(k.z >> 8) & 4095], 1);
            if ((k.w & 0xFFF00000u) == prefix) atomicAdd(&hist[(k.w >> 8) & 4095], 1);
        }
        __syncthreads();
        find_bin(hist, partial, 4096, remaining, sh3);
        prefix |= ((unsigned)sh3[0]) << 8;
        remaining -= sh3[1];
        ceqf = sh3[2];

        if (tid < 256) hist[tid] = 0;
        __syncthreads();
        for (int i = tid; i < PADN / 4; i += 1024) {
            uint4 k = kv[i];
            if ((k.x & 0xFFFFFF00u) == prefix) atomicAdd(&hist[k.x & 255], 1);
            if ((k.y & 0xFFFFFF00u) == prefix) atomicAdd(&hist[k.y & 255], 1);
            if ((k.z & 0xFFFFFF00u) == prefix) atomicAdd(&hist[k.z & 255], 1);
            if ((k.w & 0xFFFFFF00u) == prefix) atomicAdd(&hist[k.w & 255], 1);
        }
        __syncthreads();
        find_bin(hist, partial, 256, remaining, sh3);
        prefix |= (unsigned)sh3[0];
        remaining -= sh3[1];
        ceqf = sh3[2];

        const unsigned K = prefix;
        const int cgt = KC - remaining;
        const int need = remaining;
        if (tid == 0) { gcount = 0; eqtaken = 0; }
        __syncthreads();

        if (ceqf == need) {
            for (int i = tid; i < PADN / 4; i += 1024) {
                uint4 k = kv[i];
                int a0 = i * 4;
                unsigned kk[4] = {k.x, k.y, k.z, k.w};
                #pragma unroll
                for (int j = 0; j < 4; ++j) {
                    unsigned key = kk[j];
                    int a = a0 + j;
                    if (key > K) {
                        int p = atomicAdd(&gcount, 1);
                        buf[p] = compose(key, a);
                    } else if (key == K && a < NA) {
                        int p = atomicAdd(&eqtaken, 1);
                        buf[cgt + p] = compose(K, a);
                    }
                }
            }
            __syncthreads();
        } else {
            for (int bs = 0; bs < PADN; bs += 1024) {
                int a = bs + tid;
                unsigned key = colk[a];
                if (key > K) {
                    int p = atomicAdd(&gcount, 1);
                    buf[p] = compose(key, a);
                }
                bool eq = (key == K) && (a < NA);
                unsigned long long m = __ballot(eq);
                int wave = tid >> 6, lane = tid & 63;
                if (lane == 0) wcnt[wave] = __popcll(m);
                __syncthreads();
                int off = eqtaken;
                for (int w = 0; w < wave; ++w) off += wcnt[w];
                int rank = off + __popcll(m & ((1ull << lane) - 1ull));
                if (eq && rank < need)
                    buf[cgt + rank] = compose(K, a);
                __syncthreads();
                if (tid == 0) {
                    int s = 0;
                    for (int w = 0; w < 16; ++w) s += wcnt[w];
                    eqtaken += s;
                }
                __syncthreads();
            }
        }
    }

    // ---- common epilogue: bitonic sort 512 desc by composite, write out
    for (int k2 = 2; k2 <= KC; k2 <<= 1) {
        for (int j = k2 >> 1; j > 0; j >>= 1) {
            __syncthreads();
            if (tid < KC) {
                int i = tid, ixj = i ^ j;
                if (ixj > i) {
                    unsigned long long A = buf[i], B = buf[ixj];
                    bool up = (i & k2) == 0;
                    if (up ? (A < B) : (A > B)) { buf[i] = B; buf[ixj] = A; }
                }
            }
        }
    }
    __syncthreads();
    if (tid < KC) {
        unsigned long long v = buf[tid];
        unsigned key = (unsigned)(v >> 32);
        int a = (int)(0xFFFFFFFFu - (unsigned)(v & 0xFFFFFFFFu));
        top_idx[col * KC + tid] = a;
        top_score[col * KC + tid] = sigmoidf_dev(unkey(key));
    }
}

// ---- kernel 3: bitmask NMS, v3 -------------------------------------------
// 1024 threads (16 waves), register-cached j-boxes, sparse serial resolution.

__global__ __launch_bounds__(1024) void nms_kernel(const float4* __restrict__ boxes,
                                                   const int* __restrict__ top_idx,
                                                   const float* __restrict__ top_score,
                                                   float4* __restrict__ col_boxes,
                                                   float* __restrict__ col_scores) {
    const int col = blockIdx.x, b = col / NCLS;
    const int tid = threadIdx.x;
    const int wave = tid >> 6, lane = tid & 63;
    __shared__ float y1[KC], x1[KC], y2[KC], x2[KC], ar[KC], sc[KC];
    __shared__ unsigned long long maskrow[KC * 8];   // 32 KiB suppression bit-matrix
    __shared__ unsigned long long keep0w[8], keepw[8];
    __shared__ unsigned rowany[16];
    __shared__ int sel[MPC];

    if (tid < 16) rowany[tid] = 0u;
    for (int t = tid; t < KC; t += 1024) {           // waves 0-7 only; wave-uniform
        int idx = top_idx[col * KC + t];
        float4 bx = boxes[(size_t)b * NA + idx];
        y1[t] = bx.x; x1[t] = bx.y; y2[t] = bx.z; x2[t] = bx.w;
        ar[t] = __fmul_rn(fmaxf(__fsub_rn(bx.z, bx.x), 0.f),
                          fmaxf(__fsub_rn(bx.w, bx.y), 0.f));
        float s = top_score[col * KC + t];
        sc[t] = s;
        unsigned long long m = __ballot(s > 0.05f);
        if (lane == 0) keep0w[t >> 6] = m;
    }
    __syncthreads();

    // register cache: lane holds its 8 j-boxes (j = w*64 + lane)
    float jy1[8], jx1[8], jy2[8], jx2[8], jar[8];
    #pragma unroll
    for (int w = 0; w < 8; ++w) {
        int j = (w << 6) + lane;
        jy1[w] = y1[j]; jx1[w] = x1[j]; jy2[w] = y2[j]; jx2[w] = x2[j]; jar[w] = ar[j];
    }

    // build upper-triangle suppression matrix: wave handles rows i = wave+16k
    for (int i = wave; i < KC; i += 16) {
        const float iy1 = y1[i], ix1 = x1[i], iy2 = y2[i], ix2 = x2[i], iar = ar[i];
        unsigned long long any = 0ull;
        #pragma unroll
        for (int w = 0; w < 8; ++w) {
            unsigned long long m = 0ull;
            if (((w << 6) + 63) > i) {               // wave-uniform: word has some j > i
                const int j = (w << 6) + lane;
                float ih = fmaxf(__fsub_rn(fminf(iy2, jy2[w]), fmaxf(iy1, jy1[w])), 0.f);
                float iw = fmaxf(__fsub_rn(fminf(ix2, jx2[w]), fmaxf(ix1, jx1[w])), 0.f);
                float inter = __fmul_rn(ih, iw);
                float uni = __fsub_rn(__fadd_rn(iar, jar[w]), inter);
                float iou = (uni > 0.f) ? __fdiv_rn(inter, uni) : 0.f;
                m = __ballot(iou > 0.5f && j > i);
            }
            if (lane == 0) maskrow[i * 8 + w] = m;
            any |= m;
        }
        if (lane == 0 && any) atomicOr(&rowany[i >> 5], 1u << (i & 31));
    }
    __syncthreads();

    // sparse greedy resolution: LDS row loads only for alive rows with bits
    if (tid == 0) {
        unsigned long long rem[8] = {0, 0, 0, 0, 0, 0, 0, 0};
        unsigned ra[16];
        #pragma unroll
        for (int q = 0; q < 16; ++q) ra[q] = rowany[q];
        #pragma unroll
        for (int W = 0; W < 8; ++W) {
            const unsigned long long kw = keep0w[W];
            for (int t = 0; t < 64; ++t) {
                const int i = (W << 6) + t;
                bool alive = ((kw >> t) & 1ull) && !((rem[W] >> t) & 1ull);
                bool has = (ra[i >> 5] >> (i & 31)) & 1u;
                if (alive && has) {
                    const unsigned long long* row = &maskrow[i * 8];
                    #pragma unroll
                    for (int w2 = W; w2 < 8; ++w2) rem[w2] |= row[w2];
                }
            }
        }
        #pragma unroll
        for (int w = 0; w < 8; ++w) keepw[w] = keep0w[w] & ~rem[w];
        int n = 0;
        for (int t = 0; t < KC && n < MPC; ++t) if ((keepw[t >> 6] >> (t & 63)) & 1) sel[n++] = t;
        for (int t = 0; t < KC && n < MPC; ++t) if (!((keepw[t >> 6] >> (t & 63)) & 1)) sel[n++] = t;
    }
    __syncthreads();
    if (tid < MPC) {
        int t = sel[tid];
        bool kp = (keepw[t >> 6] >> (t & 63)) & 1;
        col_scores[col * MPC + tid] = kp ? sc[t] : 0.f;
        float4 o; o.x = y1[t]; o.y = x1[t]; o.z = y2[t]; o.w = x2[t];
        col_boxes[col * MPC + tid] = o;
    }
}

// ---- kernel 4: per-batch combine — LDS radix select top-100 of 8000 ------

__global__ __launch_bounds__(256) void combine_kernel(const float4* __restrict__ col_boxes,
                                                      const float* __restrict__ col_scores,
                                                      float* __restrict__ out) {
    const int b = blockIdx.x, tid = threadIdx.x;
    __shared__ unsigned long long buf[8192];
    int* hist = (int*)&buf[8000];
    int* bc = (int*)&buf[8128];
    unsigned long long* cand = &buf[8000];

    for (int t = tid; t < 8000; t += 256) {
        float s = col_scores[b * NCLS * MPC + t];
        buf[t] = ((unsigned long long)__float_as_uint(s) << 32) |
                 (unsigned long long)(0xFFFFFFFFu - (unsigned)t);
    }

    unsigned long long prefix = 0ull;
    int remaining = MT;
    for (int pass = 0; pass < 8; ++pass) {
        const int shift = 56 - 8 * pass;
        const unsigned long long mask_done = (pass == 0) ? 0ull : ((~0ull) << (shift + 8));
        __syncthreads();
        if (tid < 256) hist[tid] = 0;
        __syncthreads();
        for (int t = tid; t < 8000; t += 256) {
            unsigned long long k = buf[t];
            if ((k & mask_done) == prefix)
                atomicAdd(&hist[(int)((k >> shift) & 0xFF)], 1);
        }
        __syncthreads();
        if (tid == 0) {
            int cum = 0, bsel = 0, above = 0;
            for (int bin = 255; bin >= 0; --bin) {
                int cc = hist[bin];
                if (cum + cc >= remaining) { bsel = bin; above = cum; break; }
                cum += cc;
            }
            bc[0] = bsel; bc[1] = above;
        }
        __syncthreads();
        prefix |= ((unsigned long long)bc[0]) << shift;
        remaining -= bc[1];
    }

    int* gcnt = (int*)&buf[8128];
    __syncthreads();
    if (tid == 0) *gcnt = 0;
    if (tid < 128) cand[tid] = 0ull;
    __syncthreads();
    for (int t = tid; t < 8000; t += 256) {
        unsigned long long k = buf[t];
        if (k >= prefix) { int p = atomicAdd(gcnt, 1); cand[p] = k; }
    }
    __syncthreads();

    for (int k2 = 2; k2 <= 128; k2 <<= 1) {
        for (int j = k2 >> 1; j > 0; j >>= 1) {
            __syncthreads();
            if (tid < 128) {
                int i = tid, ixj = i ^ j;
                if (ixj > i) {
                    unsigned long long A = cand[i], B = cand[ixj];
                    bool up = (i & k2) == 0;
                    if (up ? (A < B) : (A > B)) { cand[i] = B; cand[ixj] = A; }
                }
            }
        }
    }
    __syncthreads();
    if (tid == 0) *gcnt = 0;
    __syncthreads();
    if (tid < MT) {
        unsigned long long v = cand[tid];
        float s = __uint_as_float((unsigned)(v >> 32));
        int f = (int)(0xFFFFFFFFu - (unsigned)(v & 0xFFFFFFFFu));
        bool valid = (s > 0.f);
        int cl = 0, p = 0;
        float4 bx = make_float4(0.f, 0.f, 0.f, 0.f);
        if (valid) {
            cl = f / MPC;
            p = f - cl * MPC;
            float4 raw = col_boxes[((size_t)b * NCLS + cl) * MPC + p];
            bx.x = fminf(fmaxf(raw.x, 0.f), 1.f);
            bx.y = fminf(fmaxf(raw.y, 0.f), 1.f);
            bx.z = fminf(fmaxf(raw.z, 0.f), 1.f);
            bx.w = fminf(fmaxf(raw.w, 0.f), 1.f);
            atomicAdd(gcnt, 1);
        }
        int o = b * MT + tid;
        out[o * 4 + 0] = bx.x;
        out[o * 4 + 1] = bx.y;
        out[o * 4 + 2] = bx.z;
        out[o * 4 + 3] = bx.w;
        out[NB * MT * 4 + o] = valid ? s : 0.f;
        out[NB * MT * 5 + o] = valid ? (float)cl : 0.f;
    }
    __syncthreads();
    if (tid == 0) out[NB * MT * 6 + b] = (float)(*gcnt);
}

// ---- launch --------------------------------------------------------------

extern "C" void kernel_launch(void* const* d_in, const int* in_sizes, int n_in,
                              void* d_out, int out_size, void* d_ws, size_t ws_size,
                              hipStream_t stream) {
    const float* pred = (const float*)d_in[1];
    float* out = (float*)d_out;
    char* ws = (char*)d_ws;

    Dims dims;
    const double ratios[3] = {0.5, 1.0, 2.0};
    for (int l = 0; l < 5; ++l) {
        double side = (double)(1 << (l + 5));
        double area = side * side;
        for (int ri = 0; ri < 3; ++ri) {
            double ah = sqrt(area / ratios[ri]);
            double aw = area / ah;
            for (int si = 0; si < 3; ++si) {
                double s = pow(2.0, (double)si / 3.0);
                dims.d[(l * 9 + ri * 3 + si) * 2 + 0] = (float)(s * aw);
                dims.d[(l * 9 + ri * 3 + si) * 2 + 1] = (float)(s * ah);
            }
        }
    }

    const size_t SZ_BOXES = (size_t)NB * NA * 16;            // 4,910,400
    const size_t SZ_KEYS  = (size_t)NB * NCLS * PADN * 4;    // 98,304,000

    float4*   boxes      = (float4*)(ws);
    unsigned* keys       = (unsigned*)(ws + SZ_BOXES);
    int*      top_idx    = (int*)   (ws + SZ_BOXES + SZ_KEYS);
    float*    top_score  = (float*) (ws + SZ_BOXES + SZ_KEYS + 655360);
    float4*   col_boxes  = (float4*)(ws + SZ_BOXES + SZ_KEYS + 1310720);
    float*    col_scores = (float*) (ws + SZ_BOXES + SZ_KEYS + 1822720);

    transpose_decode_kernel<<<NB * NTILE, 256, 0, stream>>>(pred, keys, boxes, dims);
    topk2_kernel<<<NB * NCLS, 1024, 0, stream>>>(keys, top_idx, top_score);
    nms_kernel<<<NB * NCLS, 1024, 0, stream>>>(boxes, top_idx, top_score, col_boxes, col_scores);
    combine_kernel<<<NB, 256, 0, stream>>>(col_boxes, col_scores, out);
}

// Round 5
// 416.456 us; speedup vs baseline: 4.5834x; 1.1443x over previous
//
#include <hip/hip_runtime.h>
#include <cmath>

#define NA 76725
#define NCLS 80
#define NB 4
#define KC 512
#define MPC 100
#define MT 100
#define TT 128          // anchors per transpose tile
#define NTILE 600       // ceil(NA/TT)
#define PADN 76800      // NA padded to multiple of 1024 (and 4)
#define CAP 4096        // candidate cap for single-histogram top-k fast path
#define SPLIT 4         // build blocks per column

struct Dims { float d[5 * 9 * 2]; };

// ---- helpers -------------------------------------------------------------

__device__ __forceinline__ unsigned keyof(float x) {
    unsigned u = __float_as_uint(x);
    return u ^ ((u & 0x80000000u) ? 0xFFFFFFFFu : 0x80000000u);
}
__device__ __forceinline__ float unkey(unsigned k) {
    unsigned u = (k & 0x80000000u) ? (k ^ 0x80000000u) : ~k;
    return __uint_as_float(u);
}
__device__ __forceinline__ float sigmoidf_dev(float x) {
    if (x >= 0.f) return 1.f / (1.f + expf(-x));
    float e = expf(x);
    return e / (1.f + e);
}
__device__ __forceinline__ unsigned long long compose(unsigned key, int a) {
    return ((unsigned long long)key << 32) | (unsigned long long)(0xFFFFFFFFu - (unsigned)a);
}

__device__ __forceinline__ float4 decode_box(float4 p, int a, const Dims& dims) {
    const int base[5] = {0, 57600, 72000, 75600, 76500};
    const int fw[5] = {80, 40, 20, 10, 5};
    const float strd[5] = {8.f, 16.f, 32.f, 64.f, 128.f};
    int l;
    if (a < 57600) l = 0;
    else if (a < 72000) l = 1;
    else if (a < 75600) l = 2;
    else if (a < 76500) l = 3;
    else l = 4;
    int i = a - base[l];
    int cell = i / 9, k = i - cell * 9;
    int x = cell % fw[l], y = cell / fw[l];
    float cx = ((float)x + 0.5f) * strd[l];
    float cy = ((float)y + 0.5f) * strd[l];
    float aw = dims.d[(l * 9 + k) * 2 + 0];
    float ah = dims.d[(l * 9 + k) * 2 + 1];
    float bx = __fmul_rn(p.x, 0.1f), by = __fmul_rn(p.y, 0.1f);
    float bw = __fmul_rn(p.z, 0.2f), bh = __fmul_rn(p.w, 0.2f);
    float4 o;
    o.x = __fadd_rn(__fmul_rn(bx, aw), cx);
    o.y = __fadd_rn(__fmul_rn(by, ah), cy);
    o.z = __fmul_rn(expf(bw), aw);
    o.w = __fmul_rn(expf(bh), ah);
    return o;
}

// ---- kernel 1: fused transpose (to sort keys) + box decode ---------------

__global__ __launch_bounds__(256) void transpose_decode_kernel(const float* __restrict__ pred,
                                                               unsigned* __restrict__ keys,
                                                               float4* __restrict__ boxes, Dims dims) {
    __shared__ float tile[TT * 84];     // 43008 B
    const int blk = blockIdx.x;
    const int b = blk / NTILE, tix = blk - b * NTILE;
    const int t0 = tix * TT;
    int nrow = NA - t0; if (nrow > TT) nrow = TT;

    const float4* src = reinterpret_cast<const float4*>(pred + ((size_t)b * NA + t0) * 84);
    const int nv = nrow * 21;
    for (int i = threadIdx.x; i < nv; i += 256)
        reinterpret_cast<float4*>(tile)[i] = src[i];
    __syncthreads();

    const int half = threadIdx.x >> 7;
    const int r = threadIdx.x & 127;
    const size_t colbase = (size_t)b * NCLS * PADN + (size_t)t0;
    for (int cc = 0; cc < 40; ++cc) {
        int c = cc * 2 + half;
        unsigned k = (r < nrow) ? keyof(tile[r * 84 + c]) : 0u;   // pads -> min key
        keys[colbase + (size_t)c * PADN + r] = k;
    }

    if (threadIdx.x < TT && r < nrow) {
        float4 p = *reinterpret_cast<const float4*>(&tile[r * 84 + 80]);
        boxes[(size_t)b * NA + t0 + r] = decode_box(p, t0 + r, dims);
    }
}

// ---- per-block reversed (high->low) histogram threshold find -------------

__device__ void find_bin(int* hist, int* partial, int bins, int remaining, int* sh3) {
    const int tid = threadIdx.x;
    const int nit = (bins + 1023) >> 10;
    int lsum = 0;
    for (int q = 0; q < nit; ++q) {
        int rr = tid * nit + q;
        if (rr < bins) lsum += hist[bins - 1 - rr];
    }
    partial[tid] = lsum;
    __syncthreads();
    int acc = lsum;
    for (int off = 1; off < 1024; off <<= 1) {
        int x = (tid >= off) ? partial[tid - off] : 0;
        __syncthreads();
        acc += x;
        partial[tid] = acc;
        __syncthreads();
    }
    int run = acc - lsum;
    for (int q = 0; q < nit; ++q) {
        int rr = tid * nit + q;
        if (rr < bins) {
            int h = hist[bins - 1 - rr];
            if (run < remaining && remaining <= run + h) { sh3[0] = bins - 1 - rr; sh3[1] = run; sh3[2] = h; }
            run += h;
        }
    }
    __syncthreads();
}

// ---- kernel 2: per-column top-512 ----------------------------------------

__global__ __launch_bounds__(1024) void topk2_kernel(const unsigned* __restrict__ keys,
                                                     int* __restrict__ top_idx,
                                                     float* __restrict__ top_score) {
    const int col = blockIdx.x;
    const int tid = threadIdx.x;
    const unsigned* colk = keys + (size_t)col * PADN;
    const uint4* kv = reinterpret_cast<const uint4*>(colk);

    __shared__ int hist[4096];
    __shared__ int partial[1024];
    __shared__ unsigned long long cand[CAP];
    __shared__ unsigned long long buf[KC];
    __shared__ int sh3[3];
    __shared__ int gcount, eqtaken;
    __shared__ int wcnt[16];

    // ---- pass 1: 12-bit coarse histogram over all keys
    for (int i = tid; i < 4096; i += 1024) hist[i] = 0;
    __syncthreads();
    for (int i = tid; i < PADN / 4; i += 1024) {
        uint4 k = kv[i];
        atomicAdd(&hist[k.x >> 20], 1);
        atomicAdd(&hist[k.y >> 20], 1);
        atomicAdd(&hist[k.z >> 20], 1);
        atomicAdd(&hist[k.w >> 20], 1);
    }
    __syncthreads();
    find_bin(hist, partial, 4096, KC, sh3);
    const int bsel = sh3[0], above = sh3[1], ceq1 = sh3[2];
    const int ncand = above + ceq1;

    if (ncand <= CAP) {
        const unsigned fk = ((unsigned)bsel) << 20;
        if (tid == 0) gcount = 0;
        __syncthreads();
        for (int i = tid; i < PADN / 4; i += 1024) {
            uint4 k = kv[i];
            int a0 = i * 4;
            if (k.x >= fk) { int p = atomicAdd(&gcount, 1); cand[p] = compose(k.x, a0 + 0); }
            if (k.y >= fk) { int p = atomicAdd(&gcount, 1); cand[p] = compose(k.y, a0 + 1); }
            if (k.z >= fk) { int p = atomicAdd(&gcount, 1); cand[p] = compose(k.z, a0 + 2); }
            if (k.w >= fk) { int p = atomicAdd(&gcount, 1); cand[p] = compose(k.w, a0 + 3); }
        }
        __syncthreads();
        const int nc = gcount;

        unsigned long long cpre = 0ull;
        int rem512 = KC;
        for (int pass = 0; pass < 8; ++pass) {
            const int shift = 56 - 8 * pass;
            const unsigned long long mdone = pass ? ((~0ull) << (shift + 8)) : 0ull;
            if (tid < 256) hist[tid] = 0;
            __syncthreads();
            for (int t = tid; t < nc; t += 1024) {
                unsigned long long k = cand[t];
                if ((k & mdone) == cpre) atomicAdd(&hist[(int)((k >> shift) & 255)], 1);
            }
            __syncthreads();
            find_bin(hist, partial, 256, rem512, sh3);
            cpre |= ((unsigned long long)(unsigned)sh3[0]) << shift;
            rem512 -= sh3[1];
            __syncthreads();
        }
        if (tid == 0) gcount = 0;
        __syncthreads();
        for (int t = tid; t < nc; t += 1024) {
            unsigned long long k = cand[t];
            if (k >= cpre) { int p = atomicAdd(&gcount, 1); buf[p] = k; }
        }
        __syncthreads();
    } else {
        unsigned prefix = ((unsigned)bsel) << 20;
        int remaining = KC - above;
        int ceqf = ceq1;

        for (int i = tid; i < 4096; i += 1024) hist[i] = 0;
        __syncthreads();
        for (int i = tid; i < PADN / 4; i += 1024) {
            uint4 k = kv[i];
            if ((k.x & 0xFFF00000u) == prefix) atomicAdd(&hist[(k.x >> 8) & 4095], 1);
            if ((k.y & 0xFFF00000u) == prefix) atomicAdd(&hist[(k.y >> 8) & 4095], 1);
            if ((k.z & 0xFFF00000u) == prefix) atomicAdd(&hist[(k.z >> 8) & 4095], 1);
            if ((k.w & 0xFFF00000u) == prefix) atomicAdd(&hist[(k.w >> 8) & 4095], 1);
        }
        __syncthreads();
        find_bin(hist, partial, 4096, remaining, sh3);
        prefix |= ((unsigned)sh3[0]) << 8;
        remaining -= sh3[1];
        ceqf = sh3[2];

        if (tid < 256) hist[tid] = 0;
        __syncthreads();
        for (int i = tid; i < PADN / 4; i += 1024) {
            uint4 k = kv[i];
            if ((k.x & 0xFFFFFF00u) == prefix) atomicAdd(&hist[k.x & 255], 1);
            if ((k.y & 0xFFFFFF00u) == prefix) atomicAdd(&hist[k.y & 255], 1);
            if ((k.z & 0xFFFFFF00u) == prefix) atomicAdd(&hist[k.z & 255], 1);
            if ((k.w & 0xFFFFFF00u) == prefix) atomicAdd(&hist[k.w & 255], 1);
        }
        __syncthreads();
        find_bin(hist, partial, 256, remaining, sh3);
        prefix |= (unsigned)sh3[0];
        remaining -= sh3[1];
        ceqf = sh3[2];

        const unsigned K = prefix;
        const int cgt = KC - remaining;
        const int need = remaining;
        if (tid == 0) { gcount = 0; eqtaken = 0; }
        __syncthreads();

        if (ceqf == need) {
            for (int i = tid; i < PADN / 4; i += 1024) {
                uint4 k = kv[i];
                int a0 = i * 4;
                unsigned kk[4] = {k.x, k.y, k.z, k.w};
                #pragma unroll
                for (int j = 0; j < 4; ++j) {
                    unsigned key = kk[j];
                    int a = a0 + j;
                    if (key > K) {
                        int p = atomicAdd(&gcount, 1);
                        buf[p] = compose(key, a);
                    } else if (key == K && a < NA) {
                        int p = atomicAdd(&eqtaken, 1);
                        buf[cgt + p] = compose(K, a);
                    }
                }
            }
            __syncthreads();
        } else {
            for (int bs = 0; bs < PADN; bs += 1024) {
                int a = bs + tid;
                unsigned key = colk[a];
                if (key > K) {
                    int p = atomicAdd(&gcount, 1);
                    buf[p] = compose(key, a);
                }
                bool eq = (key == K) && (a < NA);
                unsigned long long m = __ballot(eq);
                int wave = tid >> 6, lane = tid & 63;
                if (lane == 0) wcnt[wave] = __popcll(m);
                __syncthreads();
                int off = eqtaken;
                for (int w = 0; w < wave; ++w) off += wcnt[w];
                int rank = off + __popcll(m & ((1ull << lane) - 1ull));
                if (eq && rank < need)
                    buf[cgt + rank] = compose(K, a);
                __syncthreads();
                if (tid == 0) {
                    int s = 0;
                    for (int w = 0; w < 16; ++w) s += wcnt[w];
                    eqtaken += s;
                }
                __syncthreads();
            }
        }
    }

    // ---- common epilogue: bitonic sort 512 desc by composite, write out
    for (int k2 = 2; k2 <= KC; k2 <<= 1) {
        for (int j = k2 >> 1; j > 0; j >>= 1) {
            __syncthreads();
            if (tid < KC) {
                int i = tid, ixj = i ^ j;
                if (ixj > i) {
                    unsigned long long A = buf[i], B = buf[ixj];
                    bool up = (i & k2) == 0;
                    if (up ? (A < B) : (A > B)) { buf[i] = B; buf[ixj] = A; }
                }
            }
        }
    }
    __syncthreads();
    if (tid < KC) {
        unsigned long long v = buf[tid];
        unsigned key = (unsigned)(v >> 32);
        int a = (int)(0xFFFFFFFFu - (unsigned)(v & 0xFFFFFFFFu));
        top_idx[col * KC + tid] = a;
        top_score[col * KC + tid] = sigmoidf_dev(unkey(key));
    }
}

// ---- kernel 3a: NMS suppression-matrix build -----------------------------
// grid = 320*SPLIT blocks x 256; block handles rows i ≡ part (mod SPLIT).

__global__ __launch_bounds__(256) void nms_build_kernel(const float4* __restrict__ boxes,
                                                        const int* __restrict__ top_idx,
                                                        unsigned long long* __restrict__ maskbuf) {
    const int blk = blockIdx.x;
    const int col = blk / SPLIT, part = blk - col * SPLIT;
    const int b = col / NCLS;
    const int tid = threadIdx.x, wave = tid >> 6, lane = tid & 63;
    __shared__ float y1[KC], x1[KC], y2[KC], x2[KC], ar[KC];

    for (int t = tid; t < KC; t += 256) {
        int idx = top_idx[col * KC + t];
        float4 bx = boxes[(size_t)b * NA + idx];
        y1[t] = bx.x; x1[t] = bx.y; y2[t] = bx.z; x2[t] = bx.w;
        ar[t] = __fmul_rn(fmaxf(__fsub_rn(bx.z, bx.x), 0.f),
                          fmaxf(__fsub_rn(bx.w, bx.y), 0.f));
    }
    __syncthreads();

    // register cache: lane holds its 8 j-boxes (j = w*64 + lane)
    float jy1[8], jx1[8], jy2[8], jx2[8], jar[8];
    #pragma unroll
    for (int w = 0; w < 8; ++w) {
        int j = (w << 6) + lane;
        jy1[w] = y1[j]; jx1[w] = x1[j]; jy2[w] = y2[j]; jx2[w] = x2[j]; jar[w] = ar[j];
    }

    // rows i = part + SPLIT*(wave + 4*k), k<32  (interleaved for balance)
    for (int k = 0; k < 32; ++k) {
        const int i = part + SPLIT * (wave + 4 * k);
        const float iy1 = y1[i], ix1 = x1[i], iy2 = y2[i], ix2 = x2[i], iar = ar[i];
        unsigned long long row[8];
        #pragma unroll
        for (int w = 0; w < 8; ++w) {
            unsigned long long m = 0ull;
            if (((w << 6) + 63) > i) {               // wave-uniform: word has some j > i
                const int j = (w << 6) + lane;
                float ih = fmaxf(__fsub_rn(fminf(iy2, jy2[w]), fmaxf(iy1, jy1[w])), 0.f);
                float iw = fmaxf(__fsub_rn(fminf(ix2, jx2[w]), fmaxf(ix1, jx1[w])), 0.f);
                float inter = __fmul_rn(ih, iw);
                float uni = __fsub_rn(__fadd_rn(iar, jar[w]), inter);
                // iou > 0.5 <=> uni > 0 && inter > 0.5*uni (0.5*uni exact)
                m = __ballot((uni > 0.f) && (inter > __fmul_rn(0.5f, uni)) && (j > i));
            }
            row[w] = m;
        }
        // ballot results are wave-uniform: select row[lane] via cndmask chain, one store
        unsigned long long v = row[0];
        v = (lane == 1) ? row[1] : v;
        v = (lane == 2) ? row[2] : v;
        v = (lane == 3) ? row[3] : v;
        v = (lane == 4) ? row[4] : v;
        v = (lane == 5) ? row[5] : v;
        v = (lane == 6) ? row[6] : v;
        v = (lane == 7) ? row[7] : v;
        if (lane < 8) maskbuf[((size_t)col * KC + i) * 8 + lane] = v;
    }
}

// ---- kernel 3b: NMS greedy resolve + parallel compaction -----------------

__global__ __launch_bounds__(256) void nms_resolve_kernel(const float4* __restrict__ boxes,
                                                          const int* __restrict__ top_idx,
                                                          const float* __restrict__ top_score,
                                                          const unsigned long long* __restrict__ maskbuf,
                                                          float4* __restrict__ col_boxes,
                                                          float* __restrict__ col_scores) {
    const int col = blockIdx.x, b = col / NCLS;
    const int tid = threadIdx.x, lane = tid & 63;
    __shared__ unsigned long long mask[KC * 8];      // 32 KiB
    __shared__ float sc[KC];
    __shared__ unsigned char rowany[KC];
    __shared__ unsigned long long keep0w[8], keepw[8];
    __shared__ int wordpfx[9];
    __shared__ int sel[MPC];

    // thread t loads rows 2t, 2t+1 (8 consecutive u64 each: 2 x 64B)
    {
        const unsigned long long* src = maskbuf + (size_t)col * KC * 8;
        const int r0 = tid * 2;
        unsigned long long any0 = 0ull, any1 = 0ull;
        #pragma unroll
        for (int q = 0; q < 8; ++q) { unsigned long long v = src[r0 * 8 + q]; mask[r0 * 8 + q] = v; any0 |= v; }
        #pragma unroll
        for (int q = 0; q < 8; ++q) { unsigned long long v = src[(r0 + 1) * 8 + q]; mask[(r0 + 1) * 8 + q] = v; any1 |= v; }
        rowany[r0] = any0 ? 1 : 0;
        rowany[r0 + 1] = any1 ? 1 : 0;
    }
    for (int t = tid; t < KC; t += 256) {
        float s = top_score[col * KC + t];
        sc[t] = s;
        unsigned long long m = __ballot(s > 0.05f);
        if (lane == 0) keep0w[t >> 6] = m;
    }
    __syncthreads();

    // serial greedy: register-resident alive masks, sparse LDS row reads
    if (tid == 0) {
        unsigned long long rem[8] = {0, 0, 0, 0, 0, 0, 0, 0};
        #pragma unroll
        for (int W = 0; W < 8; ++W) {
            const unsigned long long kw = keep0w[W];
            for (int t = 0; t < 64; ++t) {
                const int i = (W << 6) + t;
                bool alive = ((kw >> t) & 1ull) && !((rem[W] >> t) & 1ull);
                if (alive && rowany[i]) {
                    const unsigned long long* row = &mask[i * 8];
                    #pragma unroll
                    for (int w2 = W; w2 < 8; ++w2) rem[w2] |= row[w2];
                }
            }
        }
        int s = 0;
        #pragma unroll
        for (int w = 0; w < 8; ++w) {
            keepw[w] = keep0w[w] & ~rem[w];
            wordpfx[w] = s;
            s += __popcll(keepw[w]);
        }
        wordpfx[8] = s;
    }
    __syncthreads();

    // parallel compaction: kept rows first (rank = kept-before), then non-kept
    const int nkept = wordpfx[8];
    for (int t = tid; t < KC; t += 256) {
        const unsigned long long w = keepw[t >> 6];
        const int l = t & 63;
        const bool kp = (w >> l) & 1ull;
        const int kb = wordpfx[t >> 6] + __popcll(w & ((1ull << l) - 1ull));
        if (kp) {
            if (kb < MPC) sel[kb] = t;
        } else {
            const int nb = t - kb;
            if (nkept + nb < MPC) sel[nkept + nb] = t;
        }
    }
    __syncthreads();
    if (tid < MPC) {
        int t = sel[tid];
        bool kp = (keepw[t >> 6] >> (t & 63)) & 1ull;
        col_scores[col * MPC + tid] = kp ? sc[t] : 0.f;
        int idx = top_idx[col * KC + t];
        col_boxes[col * MPC + tid] = boxes[(size_t)b * NA + idx];
    }
}

// ---- kernel 4: per-batch combine — LDS radix select top-100 of 8000 ------

__global__ __launch_bounds__(256) void combine_kernel(const float4* __restrict__ col_boxes,
                                                      const float* __restrict__ col_scores,
                                                      float* __restrict__ out) {
    const int b = blockIdx.x, tid = threadIdx.x;
    __shared__ unsigned long long buf[8192];
    int* hist = (int*)&buf[8000];
    int* bc = (int*)&buf[8128];
    unsigned long long* cand = &buf[8000];

    for (int t = tid; t < 8000; t += 256) {
        float s = col_scores[b * NCLS * MPC + t];
        buf[t] = ((unsigned long long)__float_as_uint(s) << 32) |
                 (unsigned long long)(0xFFFFFFFFu - (unsigned)t);
    }

    unsigned long long prefix = 0ull;
    int remaining = MT;
    for (int pass = 0; pass < 8; ++pass) {
        const int shift = 56 - 8 * pass;
        const unsigned long long mask_done = (pass == 0) ? 0ull : ((~0ull) << (shift + 8));
        __syncthreads();
        if (tid < 256) hist[tid] = 0;
        __syncthreads();
        for (int t = tid; t < 8000; t += 256) {
            unsigned long long k = buf[t];
            if ((k & mask_done) == prefix)
                atomicAdd(&hist[(int)((k >> shift) & 0xFF)], 1);
        }
        __syncthreads();
        if (tid == 0) {
            int cum = 0, bsel = 0, above = 0;
            for (int bin = 255; bin >= 0; --bin) {
                int cc = hist[bin];
                if (cum + cc >= remaining) { bsel = bin; above = cum; break; }
                cum += cc;
            }
            bc[0] = bsel; bc[1] = above;
        }
        __syncthreads();
        prefix |= ((unsigned long long)bc[0]) << shift;
        remaining -= bc[1];
    }

    int* gcnt = (int*)&buf[8128];
    __syncthreads();
    if (tid == 0) *gcnt = 0;
    if (tid < 128) cand[tid] = 0ull;
    __syncthreads();
    for (int t = tid; t < 8000; t += 256) {
        unsigned long long k = buf[t];
        if (k >= prefix) { int p = atomicAdd(gcnt, 1); cand[p] = k; }
    }
    __syncthreads();

    for (int k2 = 2; k2 <= 128; k2 <<= 1) {
        for (int j = k2 >> 1; j > 0; j >>= 1) {
            __syncthreads();
            if (tid < 128) {
                int i = tid, ixj = i ^ j;
                if (ixj > i) {
                    unsigned long long A = cand[i], B = cand[ixj];
                    bool up = (i & k2) == 0;
                    if (up ? (A < B) : (A > B)) { cand[i] = B; cand[ixj] = A; }
                }
            }
        }
    }
    __syncthreads();
    if (tid == 0) *gcnt = 0;
    __syncthreads();
    if (tid < MT) {
        unsigned long long v = cand[tid];
        float s = __uint_as_float((unsigned)(v >> 32));
        int f = (int)(0xFFFFFFFFu - (unsigned)(v & 0xFFFFFFFFu));
        bool valid = (s > 0.f);
        int cl = 0, p = 0;
        float4 bx = make_float4(0.f, 0.f, 0.f, 0.f);
        if (valid) {
            cl = f / MPC;
            p = f - cl * MPC;
            float4 raw = col_boxes[((size_t)b * NCLS + cl) * MPC + p];
            bx.x = fminf(fmaxf(raw.x, 0.f), 1.f);
            bx.y = fminf(fmaxf(raw.y, 0.f), 1.f);
            bx.z = fminf(fmaxf(raw.z, 0.f), 1.f);
            bx.w = fminf(fmaxf(raw.w, 0.f), 1.f);
            atomicAdd(gcnt, 1);
        }
        int o = b * MT + tid;
        out[o * 4 + 0] = bx.x;
        out[o * 4 + 1] = bx.y;
        out[o * 4 + 2] = bx.z;
        out[o * 4 + 3] = bx.w;
        out[NB * MT * 4 + o] = valid ? s : 0.f;
        out[NB * MT * 5 + o] = valid ? (float)cl : 0.f;
    }
    __syncthreads();
    if (tid == 0) out[NB * MT * 6 + b] = (float)(*gcnt);
}

// ---- launch --------------------------------------------------------------

extern "C" void kernel_launch(void* const* d_in, const int* in_sizes, int n_in,
                              void* d_out, int out_size, void* d_ws, size_t ws_size,
                              hipStream_t stream) {
    const float* pred = (const float*)d_in[1];
    float* out = (float*)d_out;
    char* ws = (char*)d_ws;

    Dims dims;
    const double ratios[3] = {0.5, 1.0, 2.0};
    for (int l = 0; l < 5; ++l) {
        double side = (double)(1 << (l + 5));
        double area = side * side;
        for (int ri = 0; ri < 3; ++ri) {
            double ah = sqrt(area / ratios[ri]);
            double aw = area / ah;
            for (int si = 0; si < 3; ++si) {
                double s = pow(2.0, (double)si / 3.0);
                dims.d[(l * 9 + ri * 3 + si) * 2 + 0] = (float)(s * aw);
                dims.d[(l * 9 + ri * 3 + si) * 2 + 1] = (float)(s * ah);
            }
        }
    }

    const size_t SZ_BOXES = (size_t)NB * NA * 16;            // 4,910,400
    const size_t SZ_KEYS  = (size_t)NB * NCLS * PADN * 4;    // 98,304,000

    float4*   boxes      = (float4*)(ws);
    unsigned* keys       = (unsigned*)(ws + SZ_BOXES);
    int*      top_idx    = (int*)   (ws + SZ_BOXES + SZ_KEYS);
    float*    top_score  = (float*) (ws + SZ_BOXES + SZ_KEYS + 655360);
    float4*   col_boxes  = (float4*)(ws + SZ_BOXES + SZ_KEYS + 1310720);
    float*    col_scores = (float*) (ws + SZ_BOXES + SZ_KEYS + 1822720);
    // maskbuf (10.5 MB) aliases the keys region — keys are dead after topk2,
    // and stream order guarantees topk2 completes before nms_build starts.
    unsigned long long* maskbuf = (unsigned long long*)(ws + SZ_BOXES);

    transpose_decode_kernel<<<NB * NTILE, 256, 0, stream>>>(pred, keys, boxes, dims);
    topk2_kernel<<<NB * NCLS, 1024, 0, stream>>>(keys, top_idx, top_score);
    nms_build_kernel<<<NB * NCLS * SPLIT, 256, 0, stream>>>(boxes, top_idx, maskbuf);
    nms_resolve_kernel<<<NB * NCLS, 256, 0, stream>>>(boxes, top_idx, top_score, maskbuf, col_boxes, col_scores);
    combine_kernel<<<NB, 256, 0, stream>>>(col_boxes, col_scores, out);
}

// Round 6
// 367.667 us; speedup vs baseline: 5.1916x; 1.1327x over previous
//
#include <hip/hip_runtime.h>
#include <cmath>

#define NA 76725
#define NCLS 80
#define NB 4
#define KC 512
#define MPC 100
#define MT 100
#define TT 128          // anchors per transpose tile
#define NTILE 600       // ceil(NA/TT)
#define PADN 76800      // NA padded to multiple of 1024 (and 4)
#define CAP 4096        // candidate cap for single-histogram top-k fast path
#define SPLIT 4         // build blocks per column

struct Dims { float d[5 * 9 * 2]; };

// ---- helpers -------------------------------------------------------------

__device__ __forceinline__ unsigned keyof(float x) {
    unsigned u = __float_as_uint(x);
    return u ^ ((u & 0x80000000u) ? 0xFFFFFFFFu : 0x80000000u);
}
__device__ __forceinline__ float unkey(unsigned k) {
    unsigned u = (k & 0x80000000u) ? (k ^ 0x80000000u) : ~k;
    return __uint_as_float(u);
}
__device__ __forceinline__ float sigmoidf_dev(float x) {
    if (x >= 0.f) return 1.f / (1.f + expf(-x));
    float e = expf(x);
    return e / (1.f + e);
}
__device__ __forceinline__ unsigned long long compose(unsigned key, int a) {
    return ((unsigned long long)key << 32) | (unsigned long long)(0xFFFFFFFFu - (unsigned)a);
}

__device__ __forceinline__ float4 decode_box(float4 p, int a, const Dims& dims) {
    const int base[5] = {0, 57600, 72000, 75600, 76500};
    const int fw[5] = {80, 40, 20, 10, 5};
    const float strd[5] = {8.f, 16.f, 32.f, 64.f, 128.f};
    int l;
    if (a < 57600) l = 0;
    else if (a < 72000) l = 1;
    else if (a < 75600) l = 2;
    else if (a < 76500) l = 3;
    else l = 4;
    int i = a - base[l];
    int cell = i / 9, k = i - cell * 9;
    int x = cell % fw[l], y = cell / fw[l];
    float cx = ((float)x + 0.5f) * strd[l];
    float cy = ((float)y + 0.5f) * strd[l];
    float aw = dims.d[(l * 9 + k) * 2 + 0];
    float ah = dims.d[(l * 9 + k) * 2 + 1];
    float bx = __fmul_rn(p.x, 0.1f), by = __fmul_rn(p.y, 0.1f);
    float bw = __fmul_rn(p.z, 0.2f), bh = __fmul_rn(p.w, 0.2f);
    float4 o;
    o.x = __fadd_rn(__fmul_rn(bx, aw), cx);
    o.y = __fadd_rn(__fmul_rn(by, ah), cy);
    o.z = __fmul_rn(expf(bw), aw);
    o.w = __fmul_rn(expf(bh), ah);
    return o;
}

// ---- kernel 1: fused transpose (to sort keys) + box decode ---------------

__global__ __launch_bounds__(256) void transpose_decode_kernel(const float* __restrict__ pred,
                                                               unsigned* __restrict__ keys,
                                                               float4* __restrict__ boxes, Dims dims) {
    __shared__ float tile[TT * 84];     // 43008 B
    const int blk = blockIdx.x;
    const int b = blk / NTILE, tix = blk - b * NTILE;
    const int t0 = tix * TT;
    int nrow = NA - t0; if (nrow > TT) nrow = TT;

    const float4* src = reinterpret_cast<const float4*>(pred + ((size_t)b * NA + t0) * 84);
    const int nv = nrow * 21;
    for (int i = threadIdx.x; i < nv; i += 256)
        reinterpret_cast<float4*>(tile)[i] = src[i];
    __syncthreads();

    const int half = threadIdx.x >> 7;
    const int r = threadIdx.x & 127;
    const size_t colbase = (size_t)b * NCLS * PADN + (size_t)t0;
    for (int cc = 0; cc < 40; ++cc) {
        int c = cc * 2 + half;
        unsigned k = (r < nrow) ? keyof(tile[r * 84 + c]) : 0u;   // pads -> min key
        keys[colbase + (size_t)c * PADN + r] = k;
    }

    if (threadIdx.x < TT && r < nrow) {
        float4 p = *reinterpret_cast<const float4*>(&tile[r * 84 + 80]);
        boxes[(size_t)b * NA + t0 + r] = decode_box(p, t0 + r, dims);
    }
}

// ---- per-block reversed (high->low) histogram threshold find -------------

__device__ void find_bin(int* hist, int* partial, int bins, int remaining, int* sh3) {
    const int tid = threadIdx.x;
    const int nit = (bins + 1023) >> 10;
    int lsum = 0;
    for (int q = 0; q < nit; ++q) {
        int rr = tid * nit + q;
        if (rr < bins) lsum += hist[bins - 1 - rr];
    }
    partial[tid] = lsum;
    __syncthreads();
    int acc = lsum;
    for (int off = 1; off < 1024; off <<= 1) {
        int x = (tid >= off) ? partial[tid - off] : 0;
        __syncthreads();
        acc += x;
        partial[tid] = acc;
        __syncthreads();
    }
    int run = acc - lsum;
    for (int q = 0; q < nit; ++q) {
        int rr = tid * nit + q;
        if (rr < bins) {
            int h = hist[bins - 1 - rr];
            if (run < remaining && remaining <= run + h) { sh3[0] = bins - 1 - rr; sh3[1] = run; sh3[2] = h; }
            run += h;
        }
    }
    __syncthreads();
}

// ---- kernel 2: per-column top-512 ----------------------------------------

__global__ __launch_bounds__(1024) void topk2_kernel(const unsigned* __restrict__ keys,
                                                     int* __restrict__ top_idx,
                                                     float* __restrict__ top_score) {
    const int col = blockIdx.x;
    const int tid = threadIdx.x;
    const unsigned* colk = keys + (size_t)col * PADN;
    const uint4* kv = reinterpret_cast<const uint4*>(colk);

    __shared__ int hist[4096];
    __shared__ int partial[1024];
    __shared__ unsigned long long cand[CAP];
    __shared__ unsigned long long buf[KC];
    __shared__ int sh3[3];
    __shared__ int gcount, eqtaken;
    __shared__ int wcnt[16];

    // ---- pass 1: 12-bit coarse histogram over all keys
    for (int i = tid; i < 4096; i += 1024) hist[i] = 0;
    __syncthreads();
    for (int i = tid; i < PADN / 4; i += 1024) {
        uint4 k = kv[i];
        atomicAdd(&hist[k.x >> 20], 1);
        atomicAdd(&hist[k.y >> 20], 1);
        atomicAdd(&hist[k.z >> 20], 1);
        atomicAdd(&hist[k.w >> 20], 1);
    }
    __syncthreads();
    find_bin(hist, partial, 4096, KC, sh3);
    const int bsel = sh3[0], above = sh3[1], ceq1 = sh3[2];
    const int ncand = above + ceq1;

    if (ncand <= CAP) {
        const unsigned fk = ((unsigned)bsel) << 20;
        if (tid == 0) gcount = 0;
        __syncthreads();
        for (int i = tid; i < PADN / 4; i += 1024) {
            uint4 k = kv[i];
            int a0 = i * 4;
            if (k.x >= fk) { int p = atomicAdd(&gcount, 1); cand[p] = compose(k.x, a0 + 0); }
            if (k.y >= fk) { int p = atomicAdd(&gcount, 1); cand[p] = compose(k.y, a0 + 1); }
            if (k.z >= fk) { int p = atomicAdd(&gcount, 1); cand[p] = compose(k.z, a0 + 2); }
            if (k.w >= fk) { int p = atomicAdd(&gcount, 1); cand[p] = compose(k.w, a0 + 3); }
        }
        __syncthreads();
        const int nc = gcount;

        unsigned long long cpre = 0ull;
        int rem512 = KC;
        for (int pass = 0; pass < 8; ++pass) {
            const int shift = 56 - 8 * pass;
            const unsigned long long mdone = pass ? ((~0ull) << (shift + 8)) : 0ull;
            if (tid < 256) hist[tid] = 0;
            __syncthreads();
            for (int t = tid; t < nc; t += 1024) {
                unsigned long long k = cand[t];
                if ((k & mdone) == cpre) atomicAdd(&hist[(int)((k >> shift) & 255)], 1);
            }
            __syncthreads();
            find_bin(hist, partial, 256, rem512, sh3);
            cpre |= ((unsigned long long)(unsigned)sh3[0]) << shift;
            rem512 -= sh3[1];
            __syncthreads();
        }
        if (tid == 0) gcount = 0;
        __syncthreads();
        for (int t = tid; t < nc; t += 1024) {
            unsigned long long k = cand[t];
            if (k >= cpre) { int p = atomicAdd(&gcount, 1); buf[p] = k; }
        }
        __syncthreads();
    } else {
        unsigned prefix = ((unsigned)bsel) << 20;
        int remaining = KC - above;
        int ceqf = ceq1;

        for (int i = tid; i < 4096; i += 1024) hist[i] = 0;
        __syncthreads();
        for (int i = tid; i < PADN / 4; i += 1024) {
            uint4 k = kv[i];
            if ((k.x & 0xFFF00000u) == prefix) atomicAdd(&hist[(k.x >> 8) & 4095], 1);
            if ((k.y & 0xFFF00000u) == prefix) atomicAdd(&hist[(k.y >> 8) & 4095], 1);
            if ((k.z & 0xFFF00000u) == prefix) atomicAdd(&hist[(k.z >> 8) & 4095], 1);
            if ((k.w & 0xFFF00000u) == prefix) atomicAdd(&hist[(k.w >> 8) & 4095], 1);
        }
        __syncthreads();
        find_bin(hist, partial, 4096, remaining, sh3);
        prefix |= ((unsigned)sh3[0]) << 8;
        remaining -= sh3[1];
        ceqf = sh3[2];

        if (tid < 256) hist[tid] = 0;
        __syncthreads();
        for (int i = tid; i < PADN / 4; i += 1024) {
            uint4 k = kv[i];
            if ((k.x & 0xFFFFFF00u) == prefix) atomicAdd(&hist[k.x & 255], 1);
            if ((k.y & 0xFFFFFF00u) == prefix) atomicAdd(&hist[k.y & 255], 1);
            if ((k.z & 0xFFFFFF00u) == prefix) atomicAdd(&hist[k.z & 255], 1);
            if ((k.w & 0xFFFFFF00u) == prefix) atomicAdd(&hist[k.w & 255], 1);
        }
        __syncthreads();
        find_bin(hist, partial, 256, remaining, sh3);
        prefix |= (unsigned)sh3[0];
        remaining -= sh3[1];
        ceqf = sh3[2];

        const unsigned K = prefix;
        const int cgt = KC - remaining;
        const int need = remaining;
        if (tid == 0) { gcount = 0; eqtaken = 0; }
        __syncthreads();

        if (ceqf == need) {
            for (int i = tid; i < PADN / 4; i += 1024) {
                uint4 k = kv[i];
                int a0 = i * 4;
                unsigned kk[4] = {k.x, k.y, k.z, k.w};
                #pragma unroll
                for (int j = 0; j < 4; ++j) {
                    unsigned key = kk[j];
                    int a = a0 + j;
                    if (key > K) {
                        int p = atomicAdd(&gcount, 1);
                        buf[p] = compose(key, a);
                    } else if (key == K && a < NA) {
                        int p = atomicAdd(&eqtaken, 1);
                        buf[cgt + p] = compose(K, a);
                    }
                }
            }
            __syncthreads();
        } else {
            for (int bs = 0; bs < PADN; bs += 1024) {
                int a = bs + tid;
                unsigned key = colk[a];
                if (key > K) {
                    int p = atomicAdd(&gcount, 1);
                    buf[p] = compose(key, a);
                }
                bool eq = (key == K) && (a < NA);
                unsigned long long m = __ballot(eq);
                int wave = tid >> 6, lane = tid & 63;
                if (lane == 0) wcnt[wave] = __popcll(m);
                __syncthreads();
                int off = eqtaken;
                for (int w = 0; w < wave; ++w) off += wcnt[w];
                int rank = off + __popcll(m & ((1ull << lane) - 1ull));
                if (eq && rank < need)
                    buf[cgt + rank] = compose(K, a);
                __syncthreads();
                if (tid == 0) {
                    int s = 0;
                    for (int w = 0; w < 16; ++w) s += wcnt[w];
                    eqtaken += s;
                }
                __syncthreads();
            }
        }
    }

    // ---- common epilogue: bitonic sort 512 desc by composite, write out
    for (int k2 = 2; k2 <= KC; k2 <<= 1) {
        for (int j = k2 >> 1; j > 0; j >>= 1) {
            __syncthreads();
            if (tid < KC) {
                int i = tid, ixj = i ^ j;
                if (ixj > i) {
                    unsigned long long A = buf[i], B = buf[ixj];
                    bool up = (i & k2) == 0;
                    if (up ? (A < B) : (A > B)) { buf[i] = B; buf[ixj] = A; }
                }
            }
        }
    }
    __syncthreads();
    if (tid < KC) {
        unsigned long long v = buf[tid];
        unsigned key = (unsigned)(v >> 32);
        int a = (int)(0xFFFFFFFFu - (unsigned)(v & 0xFFFFFFFFu));
        top_idx[col * KC + tid] = a;
        top_score[col * KC + tid] = sigmoidf_dev(unkey(key));
    }
}

// ---- kernel 3a: NMS suppression-matrix build -----------------------------

__global__ __launch_bounds__(256) void nms_build_kernel(const float4* __restrict__ boxes,
                                                        const int* __restrict__ top_idx,
                                                        unsigned long long* __restrict__ maskbuf) {
    const int blk = blockIdx.x;
    const int col = blk / SPLIT, part = blk - col * SPLIT;
    const int b = col / NCLS;
    const int tid = threadIdx.x, wave = tid >> 6, lane = tid & 63;
    __shared__ float y1[KC], x1[KC], y2[KC], x2[KC], ar[KC];

    for (int t = tid; t < KC; t += 256) {
        int idx = top_idx[col * KC + t];
        float4 bx = boxes[(size_t)b * NA + idx];
        y1[t] = bx.x; x1[t] = bx.y; y2[t] = bx.z; x2[t] = bx.w;
        ar[t] = __fmul_rn(fmaxf(__fsub_rn(bx.z, bx.x), 0.f),
                          fmaxf(__fsub_rn(bx.w, bx.y), 0.f));
    }
    __syncthreads();

    float jy1[8], jx1[8], jy2[8], jx2[8], jar[8];
    #pragma unroll
    for (int w = 0; w < 8; ++w) {
        int j = (w << 6) + lane;
        jy1[w] = y1[j]; jx1[w] = x1[j]; jy2[w] = y2[j]; jx2[w] = x2[j]; jar[w] = ar[j];
    }

    for (int k = 0; k < 32; ++k) {
        const int i = part + SPLIT * (wave + 4 * k);
        const float iy1 = y1[i], ix1 = x1[i], iy2 = y2[i], ix2 = x2[i], iar = ar[i];
        unsigned long long row[8];
        #pragma unroll
        for (int w = 0; w < 8; ++w) {
            unsigned long long m = 0ull;
            if (((w << 6) + 63) > i) {
                const int j = (w << 6) + lane;
                float ih = fmaxf(__fsub_rn(fminf(iy2, jy2[w]), fmaxf(iy1, jy1[w])), 0.f);
                float iw = fmaxf(__fsub_rn(fminf(ix2, jx2[w]), fmaxf(ix1, jx1[w])), 0.f);
                float inter = __fmul_rn(ih, iw);
                float uni = __fsub_rn(__fadd_rn(iar, jar[w]), inter);
                m = __ballot((uni > 0.f) && (inter > __fmul_rn(0.5f, uni)) && (j > i));
            }
            row[w] = m;
        }
        unsigned long long v = row[0];
        v = (lane == 1) ? row[1] : v;
        v = (lane == 2) ? row[2] : v;
        v = (lane == 3) ? row[3] : v;
        v = (lane == 4) ? row[4] : v;
        v = (lane == 5) ? row[5] : v;
        v = (lane == 6) ? row[6] : v;
        v = (lane == 7) ? row[7] : v;
        if (lane < 8) maskbuf[((size_t)col * KC + i) * 8 + lane] = v;
    }
}

// ---- kernel 3b: NMS greedy resolve + parallel compaction -----------------

__global__ __launch_bounds__(256) void nms_resolve_kernel(const float4* __restrict__ boxes,
                                                          const int* __restrict__ top_idx,
                                                          const float* __restrict__ top_score,
                                                          const unsigned long long* __restrict__ maskbuf,
                                                          float4* __restrict__ col_boxes,
                                                          float* __restrict__ col_scores) {
    const int col = blockIdx.x, b = col / NCLS;
    const int tid = threadIdx.x, lane = tid & 63;
    __shared__ unsigned long long mask[KC * 8];      // 32 KiB
    __shared__ float sc[KC];
    __shared__ unsigned char rowany[KC];
    __shared__ unsigned long long keep0w[8], keepw[8];
    __shared__ int wordpfx[9];
    __shared__ int sel[MPC];

    {
        const unsigned long long* src = maskbuf + (size_t)col * KC * 8;
        const int r0 = tid * 2;
        unsigned long long any0 = 0ull, any1 = 0ull;
        #pragma unroll
        for (int q = 0; q < 8; ++q) { unsigned long long v = src[r0 * 8 + q]; mask[r0 * 8 + q] = v; any0 |= v; }
        #pragma unroll
        for (int q = 0; q < 8; ++q) { unsigned long long v = src[(r0 + 1) * 8 + q]; mask[(r0 + 1) * 8 + q] = v; any1 |= v; }
        rowany[r0] = any0 ? 1 : 0;
        rowany[r0 + 1] = any1 ? 1 : 0;
    }
    for (int t = tid; t < KC; t += 256) {
        float s = top_score[col * KC + t];
        sc[t] = s;
        unsigned long long m = __ballot(s > 0.05f);
        if (lane == 0) keep0w[t >> 6] = m;
    }
    __syncthreads();

    if (tid == 0) {
        unsigned long long rem[8] = {0, 0, 0, 0, 0, 0, 0, 0};
        #pragma unroll
        for (int W = 0; W < 8; ++W) {
            const unsigned long long kw = keep0w[W];
            for (int t = 0; t < 64; ++t) {
                const int i = (W << 6) + t;
                bool alive = ((kw >> t) & 1ull) && !((rem[W] >> t) & 1ull);
                if (alive && rowany[i]) {
                    const unsigned long long* row = &mask[i * 8];
                    #pragma unroll
                    for (int w2 = W; w2 < 8; ++w2) rem[w2] |= row[w2];
                }
            }
        }
        int s = 0;
        #pragma unroll
        for (int w = 0; w < 8; ++w) {
            keepw[w] = keep0w[w] & ~rem[w];
            wordpfx[w] = s;
            s += __popcll(keepw[w]);
        }
        wordpfx[8] = s;
    }
    __syncthreads();

    const int nkept = wordpfx[8];
    for (int t = tid; t < KC; t += 256) {
        const unsigned long long w = keepw[t >> 6];
        const int l = t & 63;
        const bool kp = (w >> l) & 1ull;
        const int kb = wordpfx[t >> 6] + __popcll(w & ((1ull << l) - 1ull));
        if (kp) {
            if (kb < MPC) sel[kb] = t;
        } else {
            const int nb = t - kb;
            if (nkept + nb < MPC) sel[nkept + nb] = t;
        }
    }
    __syncthreads();
    if (tid < MPC) {
        int t = sel[tid];
        bool kp = (keepw[t >> 6] >> (t & 63)) & 1ull;
        col_scores[col * MPC + tid] = kp ? sc[t] : 0.f;
        int idx = top_idx[col * KC + t];
        col_boxes[col * MPC + tid] = boxes[(size_t)b * NA + idx];
    }
}

// ---- kernel 4: per-batch combine v3 — register keys, parallel bin scan ---
// top-100 of 8000 by (score desc, idx asc). Scores >= 0 so raw float bits
// are unsigned-monotone. 4x8-bit radix over score with parallel reversed
// scan; exact index tie-break via ordered ballot scan (rare path).

__global__ __launch_bounds__(256) void combine_kernel(const float4* __restrict__ col_boxes,
                                                      const float* __restrict__ col_scores,
                                                      float* __restrict__ out) {
    const int b = blockIdx.x, tid = threadIdx.x;
    const int wv = tid >> 6, lane = tid & 63;
    __shared__ int hist[256];
    __shared__ int partial[256];
    __shared__ unsigned long long cand[128];
    __shared__ int sh3[3];
    __shared__ int gcnt, eqtaken;
    __shared__ int wcnt[4];

    // registers: thread owns elements t = q*256 + tid, q < 32 (t<8000)
    unsigned sck[32];
    #pragma unroll
    for (int q = 0; q < 32; ++q) {
        const bool ok = (q < 31) || (tid < 64);
        sck[q] = ok ? __float_as_uint(col_scores[b * NCLS * MPC + (q << 8) + tid]) : 0u;
    }

    unsigned prefix = 0;
    int remaining = MT, ceq = 0;
    #pragma unroll 1
    for (int pass = 0; pass < 4; ++pass) {
        const int shift = 24 - 8 * pass;
        const unsigned mdone = pass ? (0xFFFFFFFFu << (shift + 8)) : 0u;
        hist[tid] = 0;
        __syncthreads();
        #pragma unroll
        for (int q = 0; q < 32; ++q) {
            const bool ok = (q < 31) || (tid < 64);
            if (ok && (sck[q] & mdone) == prefix)
                atomicAdd(&hist[(sck[q] >> shift) & 255], 1);
        }
        __syncthreads();
        // parallel reversed (high->low) exclusive scan over 256 bins
        int lsum = hist[255 - tid];
        partial[tid] = lsum;
        __syncthreads();
        int acc = lsum;
        for (int off = 1; off < 256; off <<= 1) {
            int x = (tid >= off) ? partial[tid - off] : 0;
            __syncthreads();
            acc += x;
            partial[tid] = acc;
            __syncthreads();
        }
        int run = acc - lsum;   // count strictly above my bin
        if (run < remaining && remaining <= run + lsum) { sh3[0] = 255 - tid; sh3[1] = run; sh3[2] = lsum; }
        __syncthreads();
        prefix |= ((unsigned)sh3[0]) << shift;
        remaining -= sh3[1];
        ceq = sh3[2];
        __syncthreads();
    }
    const unsigned S = prefix;          // exact 100th-largest score (bits)
    const int cgt = MT - remaining;     // count strictly greater than S

    if (tid == 0) { gcnt = 0; eqtaken = 0; }
    if (tid < 128) cand[tid] = 0ull;
    __syncthreads();
    #pragma unroll
    for (int q = 0; q < 32; ++q) {
        const bool ok = (q < 31) || (tid < 64);
        if (ok && sck[q] > S) {
            int p = atomicAdd(&gcnt, 1);
            int t = (q << 8) + tid;
            cand[p] = ((unsigned long long)sck[q] << 32) |
                      (unsigned long long)(0xFFFFFFFFu - (unsigned)t);
        }
    }
    __syncthreads();

    if (ceq == remaining) {
        // all score==S elements taken; order fixed by final sort
        #pragma unroll
        for (int q = 0; q < 32; ++q) {
            const bool ok = (q < 31) || (tid < 64);
            if (ok && sck[q] == S) {
                int p = atomicAdd(&eqtaken, 1);
                int t = (q << 8) + tid;
                cand[cgt + p] = ((unsigned long long)S << 32) |
                                (unsigned long long)(0xFFFFFFFFu - (unsigned)t);
            }
        }
        __syncthreads();
    } else {
        // ordered scan: smallest-index `remaining` among score==S
        #pragma unroll 1
        for (int q = 0; q < 32; ++q) {
            const bool ok = (q < 31) || (tid < 64);
            const bool eq = ok && (sck[q] == S);
            unsigned long long m = __ballot(eq);
            if (lane == 0) wcnt[wv] = __popcll(m);
            __syncthreads();
            int off = eqtaken;
            for (int w = 0; w < wv; ++w) off += wcnt[w];
            int rank = off + __popcll(m & ((1ull << lane) - 1ull));
            if (eq && rank < remaining) {
                int t = (q << 8) + tid;
                cand[cgt + rank] = ((unsigned long long)S << 32) |
                                   (unsigned long long)(0xFFFFFFFFu - (unsigned)t);
            }
            __syncthreads();
            if (tid == 0) eqtaken += wcnt[0] + wcnt[1] + wcnt[2] + wcnt[3];
            __syncthreads();
        }
    }

    // bitonic sort 128 desc by composite (score desc, idx asc)
    for (int k2 = 2; k2 <= 128; k2 <<= 1) {
        for (int j = k2 >> 1; j > 0; j >>= 1) {
            __syncthreads();
            if (tid < 128) {
                int i = tid, ixj = i ^ j;
                if (ixj > i) {
                    unsigned long long A = cand[i], B = cand[ixj];
                    bool up = (i & k2) == 0;
                    if (up ? (A < B) : (A > B)) { cand[i] = B; cand[ixj] = A; }
                }
            }
        }
    }
    __syncthreads();
    if (tid == 0) gcnt = 0;
    __syncthreads();
    if (tid < MT) {
        unsigned long long v = cand[tid];
        float s = __uint_as_float((unsigned)(v >> 32));
        int f = (int)(0xFFFFFFFFu - (unsigned)(v & 0xFFFFFFFFu));
        bool valid = (s > 0.f);
        int cl = 0, p = 0;
        float4 bx = make_float4(0.f, 0.f, 0.f, 0.f);
        if (valid) {
            cl = f / MPC;
            p = f - cl * MPC;
            float4 raw = col_boxes[((size_t)b * NCLS + cl) * MPC + p];
            bx.x = fminf(fmaxf(raw.x, 0.f), 1.f);
            bx.y = fminf(fmaxf(raw.y, 0.f), 1.f);
            bx.z = fminf(fmaxf(raw.z, 0.f), 1.f);
            bx.w = fminf(fmaxf(raw.w, 0.f), 1.f);
            atomicAdd(&gcnt, 1);
        }
        int o = b * MT + tid;
        out[o * 4 + 0] = bx.x;
        out[o * 4 + 1] = bx.y;
        out[o * 4 + 2] = bx.z;
        out[o * 4 + 3] = bx.w;
        out[NB * MT * 4 + o] = valid ? s : 0.f;
        out[NB * MT * 5 + o] = valid ? (float)cl : 0.f;
    }
    __syncthreads();
    if (tid == 0) out[NB * MT * 6 + b] = (float)gcnt;
}

// ---- launch --------------------------------------------------------------

extern "C" void kernel_launch(void* const* d_in, const int* in_sizes, int n_in,
                              void* d_out, int out_size, void* d_ws, size_t ws_size,
                              hipStream_t stream) {
    const float* pred = (const float*)d_in[1];
    float* out = (float*)d_out;
    char* ws = (char*)d_ws;

    Dims dims;
    const double ratios[3] = {0.5, 1.0, 2.0};
    for (int l = 0; l < 5; ++l) {
        double side = (double)(1 << (l + 5));
        double area = side * side;
        for (int ri = 0; ri < 3; ++ri) {
            double ah = sqrt(area / ratios[ri]);
            double aw = area / ah;
            for (int si = 0; si < 3; ++si) {
                double s = pow(2.0, (double)si / 3.0);
                dims.d[(l * 9 + ri * 3 + si) * 2 + 0] = (float)(s * aw);
                dims.d[(l * 9 + ri * 3 + si) * 2 + 1] = (float)(s * ah);
            }
        }
    }

    const size_t SZ_BOXES = (size_t)NB * NA * 16;            // 4,910,400
    const size_t SZ_KEYS  = (size_t)NB * NCLS * PADN * 4;    // 98,304,000

    float4*   boxes      = (float4*)(ws);
    unsigned* keys       = (unsigned*)(ws + SZ_BOXES);
    int*      top_idx    = (int*)   (ws + SZ_BOXES + SZ_KEYS);
    float*    top_score  = (float*) (ws + SZ_BOXES + SZ_KEYS + 655360);
    float4*   col_boxes  = (float4*)(ws + SZ_BOXES + SZ_KEYS + 1310720);
    float*    col_scores = (float*) (ws + SZ_BOXES + SZ_KEYS + 1822720);
    // maskbuf (10.5 MB) aliases the keys region — keys are dead after topk2.
    unsigned long long* maskbuf = (unsigned long long*)(ws + SZ_BOXES);

    transpose_decode_kernel<<<NB * NTILE, 256, 0, stream>>>(pred, keys, boxes, dims);
    topk2_kernel<<<NB * NCLS, 1024, 0, stream>>>(keys, top_idx, top_score);
    nms_build_kernel<<<NB * NCLS * SPLIT, 256, 0, stream>>>(boxes, top_idx, maskbuf);
    nms_resolve_kernel<<<NB * NCLS, 256, 0, stream>>>(boxes, top_idx, top_score, maskbuf, col_boxes, col_scores);
    combine_kernel<<<NB, 256, 0, stream>>>(col_boxes, col_scores, out);
}